// Round 17
// baseline (598.671 us; speedup 1.0000x reference)
//
#include <hip/hip_runtime.h>
#include <hip/hip_bf16.h>
#include <math.h>

#define NN 262144
#define NE 2097152
#define NG 8192
#define THREADS 256

typedef __hip_bfloat16 bf16;
typedef __attribute__((ext_vector_type(8))) short short8v;   // 8 bf16 (4 VGPRs)
typedef __attribute__((ext_vector_type(4))) float f32x4;

static __device__ __forceinline__ float lrelu(float x){ return x > 0.f ? x : 0.01f*x; }
static __device__ __forceinline__ float eluf(float x){ return x > 0.f ? x : __expf(x) - 1.f; }
static __device__ __forceinline__ float sigm(float x){ return 1.f/(1.f + __expf(-x)); }
static __device__ __forceinline__ float tanh_fast(float x){
  float e = __expf(2.f*x); return 1.f - 2.f/(e + 1.f);
}
static __device__ __forceinline__ float b2f(bf16 v){ return __bfloat162float(v); }
static __device__ __forceinline__ bf16 f2b(float v){ return __float2bfloat16(v); }
// bit-reinterpret a raw bf16 (held in a short) to float — NEVER value-convert!
static __device__ __forceinline__ float s2f(short s){
  return __uint_as_float(((unsigned int)(unsigned short)s) << 16);
}

static __device__ __forceinline__ unsigned short bfbits(float f){
  union { bf16 b; unsigned short s; } u; u.b = f2b(f); return u.s;
}
static __device__ __forceinline__ unsigned int pack2(float lo, float hi){
  return (unsigned int)bfbits(lo) | ((unsigned int)bfbits(hi) << 16);
}

static __device__ __forceinline__ float redsum32(float t){
  #pragma unroll
  for (int o = 16; o > 0; o >>= 1) t += __shfl_xor(t, o, 32);
  return t;
}

// GRU helper for the readout kernel (32 lanes = one row)
static __device__ __forceinline__ float gru_relu(float hv, float xv, int c,
    const float* __restrict__ wih, const float* __restrict__ whh,
    const float* __restrict__ bih, const float* __restrict__ bhh){
  float gr = bih[c], gz = bih[32+c], gn = bih[64+c];
  float hr = bhh[c], hz = bhh[32+c], hn = bhh[64+c];
  #pragma unroll 8
  for (int k = 0; k < 32; k++){
    float hk = __shfl(hv, k, 32);
    float xk = __shfl(xv, k, 32);
    gr += hk*wih[(     c)*32 + k];
    gz += hk*wih[(32 + c)*32 + k];
    gn += hk*wih[(64 + c)*32 + k];
    hr += xk*whh[(     c)*32 + k];
    hz += xk*whh[(32 + c)*32 + k];
    hn += xk*whh[(64 + c)*32 + k];
  }
  float r = sigm(gr + hr), z = sigm(gz + hz);
  float nn2 = tanh_fast(gn + r*hn);
  return fmaxf((1.f - z)*nn2 + z*xv, 0.f);
}

__global__ __launch_bounds__(THREADS) void k_filli(int* __restrict__ p, int v, int n){
  int i = blockIdx.x*THREADS + threadIdx.x;
  if (i < n) p[i] = v;
}

// ================= FRONT mega-kernel: embed (MFMA) ∥ histrank ∥ gptr ==========
#define FB_EMBED 512
#define FB_HIST  8192
#define FB_GPTR  1024

__global__ __launch_bounds__(THREADS) void k_front(
    const float* __restrict__ xin, const float* __restrict__ lw, const float* __restrict__ lb,
    const float* __restrict__ w1, const float* __restrict__ w2,
    const float* __restrict__ attr_r, float* __restrict__ X,
    bf16* __restrict__ u, bf16* __restrict__ v, float* __restrict__ nr,
    const int* __restrict__ ei, int* __restrict__ hist, int* __restrict__ rank,
    const int* __restrict__ batch, int* __restrict__ gptr){
  __shared__ float ol[4][16][33];
  int bid = blockIdx.x;
  if (bid < FB_EMBED){
    int wid  = bid*4 + (threadIdx.x >> 6);
    int wv   = threadIdx.x >> 6;
    int lane = threadIdx.x & 63;
    int cl = lane & 15;
    int kb = lane >> 4;
    short8v BL[2][2], BU[2], BV[2];
    #pragma unroll
    for (int g = 0; g < 2; g++){
      #pragma unroll
      for (int kc = 0; kc < 2; kc++){
        short8v t;
        #pragma unroll
        for (int j = 0; j < 8; j++){
          int k = kc*32 + kb*8 + j;
          t[j] = (k < 54) ? (short)bfbits(lw[(size_t)(g*16+cl)*54 + k]) : (short)0;
        }
        BL[g][kc] = t;
      }
      short8v tu, tv;
      #pragma unroll
      for (int j = 0; j < 8; j++){
        tu[j] = (short)bfbits(w1[(size_t)(g*16+cl)*33 + kb*8 + j]);
        tv[j] = (short)bfbits(w2[(size_t)(g*16+cl)*32 + kb*8 + j]);
      }
      BU[g] = tu; BV[g] = tv;
    }
    float bb0 = lb[cl], bb1 = lb[16+cl];
    float ar0 = attr_r[cl], ar1 = attr_r[16+cl];
    f32x4 zero; zero[0]=0.f; zero[1]=0.f; zero[2]=0.f; zero[3]=0.f;

    for (int t = 0; t < 8; t++){
      int nb = (wid*8 + t)*16;
      const float* xrow = xin + (size_t)(nb + cl)*54;
      short8v Ax0, Ax1;
      const float2* x2 = (const float2*)(xrow + kb*8);
      #pragma unroll
      for (int jj = 0; jj < 4; jj++){
        float2 tvv = x2[jj];
        Ax0[2*jj]   = (short)bfbits(tvv.x);
        Ax0[2*jj+1] = (short)bfbits(tvv.y);
      }
      #pragma unroll
      for (int j = 0; j < 8; j++){
        int k = 32 + kb*8 + j;
        Ax1[j] = (k < 54) ? (short)bfbits(xrow[k]) : (short)0;
      }
      f32x4 a0, a1;
      #pragma unroll
      for (int q = 0; q < 4; q++){ a0[q] = bb0; a1[q] = bb1; }
      f32x4 d0 = __builtin_amdgcn_mfma_f32_16x16x32_bf16(Ax0, BL[0][0], a0, 0, 0, 0);
      d0 = __builtin_amdgcn_mfma_f32_16x16x32_bf16(Ax1, BL[0][1], d0, 0, 0, 0);
      f32x4 d1 = __builtin_amdgcn_mfma_f32_16x16x32_bf16(Ax0, BL[1][0], a1, 0, 0, 0);
      d1 = __builtin_amdgcn_mfma_f32_16x16x32_bf16(Ax1, BL[1][1], d1, 0, 0, 0);
      #pragma unroll
      for (int r = 0; r < 4; r++){ d0[r] = lrelu(d0[r]); d1[r] = lrelu(d1[r]); }
      #pragma unroll
      for (int r = 0; r < 4; r++){
        int node = nb + kb*4 + r;
        float* srow = X + (size_t)node*32;
        srow[cl]      = d0[r];
        srow[16 + cl] = d1[r];
        ol[wv][kb*4 + r][cl]      = d0[r];
        ol[wv][kb*4 + r][16 + cl] = d1[r];
      }
      #pragma unroll
      for (int r = 0; r < 4; r++){
        float vsum = d0[r]*ar0 + d1[r]*ar1;
        vsum += __shfl_xor(vsum, 1, 16);
        vsum += __shfl_xor(vsum, 2, 16);
        vsum += __shfl_xor(vsum, 4, 16);
        vsum += __shfl_xor(vsum, 8, 16);
        if (cl == 0) nr[nb + kb*4 + r] = vsum;
      }
      __syncthreads();
      short8v Ao;
      #pragma unroll
      for (int j = 0; j < 8; j++) Ao[j] = (short)bfbits(ol[wv][cl][kb*8 + j]);
      f32x4 u0 = __builtin_amdgcn_mfma_f32_16x16x32_bf16(Ao, BU[0], zero, 0, 0, 0);
      f32x4 u1 = __builtin_amdgcn_mfma_f32_16x16x32_bf16(Ao, BU[1], zero, 0, 0, 0);
      f32x4 v0 = __builtin_amdgcn_mfma_f32_16x16x32_bf16(Ao, BV[0], zero, 0, 0, 0);
      f32x4 v1 = __builtin_amdgcn_mfma_f32_16x16x32_bf16(Ao, BV[1], zero, 0, 0, 0);
      #pragma unroll
      for (int r = 0; r < 4; r++){
        int node = nb + kb*4 + r;
        bf16* ur = u + (size_t)node*32;
        bf16* vr = v + (size_t)node*32;
        ur[cl]      = f2b(u0[r]);
        ur[16 + cl] = f2b(u1[r]);
        vr[cl]      = f2b(v0[r]);
        vr[16 + cl] = f2b(v1[r]);
      }
      __syncthreads();
    }
  } else if (bid < FB_EMBED + FB_HIST){
    int e = (bid - FB_EMBED)*THREADS + threadIdx.x;
    rank[e] = atomicAdd(hist + ei[NE + e], 1);
  } else {
    int n = (bid - FB_EMBED - FB_HIST)*THREADS + threadIdx.x;
    int bc = batch[n];
    if (n == 0){ for (int g = 0; g <= bc; g++) gptr[g] = 0; }
    else {
      int pb = batch[n-1];
      if (pb != bc) for (int g = pb+1; g <= bc; g++) gptr[g] = n;
    }
    if (n == NN-1){ for (int g = bc+1; g <= NG; g++) gptr[g] = NN; }
  }
}

// ---------------- scans ----------------
__global__ __launch_bounds__(THREADS) void k_scan1(const int* __restrict__ hist,
    int* __restrict__ rp1, int* __restrict__ btot){
  __shared__ int sh[THREADS];
  int i = blockIdx.x*THREADS + threadIdx.x;
  int v = hist[i];
  sh[threadIdx.x] = v; __syncthreads();
  #pragma unroll
  for (int off = 1; off < THREADS; off <<= 1){
    int t = (threadIdx.x >= off) ? sh[threadIdx.x - off] : 0;
    __syncthreads(); sh[threadIdx.x] += t; __syncthreads();
  }
  rp1[i] = sh[threadIdx.x] - v;
  if (threadIdx.x == THREADS-1) btot[blockIdx.x] = sh[THREADS-1];
}

__global__ __launch_bounds__(1024) void k_scan2(int* __restrict__ btot){
  __shared__ int sh[1024];
  int i = threadIdx.x;
  int v = btot[i];
  sh[i] = v; __syncthreads();
  for (int off = 1; off < 1024; off <<= 1){
    int t = (i >= off) ? sh[i - off] : 0;
    __syncthreads(); sh[i] += t; __syncthreads();
  }
  btot[i] = sh[i] - v;  // exclusive
}

// ======== MID mega-kernel: final rowptr ∥ atomic-free place ==================
#define MB_SCAN 1024

__global__ __launch_bounds__(THREADS) void k_mid(const int* __restrict__ rp1,
    const int* __restrict__ btot, int* __restrict__ rowptr,
    const int* __restrict__ ei, const float* __restrict__ ea,
    const int* __restrict__ rank, int2* __restrict__ epk){
  int bid = blockIdx.x;
  if (bid < MB_SCAN){
    int i = bid*THREADS + threadIdx.x;
    rowptr[i] = rp1[i] + btot[i >> 8];
    if (i == 0) rowptr[NN] = NE;
  } else {
    int e = (bid - MB_SCAN)*THREADS + threadIdx.x;
    int d = ei[NE + e];
    int pos = rp1[d] + btot[d >> 8] + rank[e];
    epk[pos] = make_int2(ei[e], __float_as_int(ea[e]));
  }
}

// ======== conv+GRU fused: block = 64 nodes ===================================
// Phase 1 (8 groups x 8 nodes): no-max softmax conv; h rows -> LDS.
// Phase 2 (4 waves x 16-node tile): MFMA GRU + att precompute (xt, s1, s2).
__global__ __launch_bounds__(THREADS) void k_conv_gru(const int* __restrict__ rowptr,
    const int2* __restrict__ epk, const bf16* __restrict__ U,
    const float* __restrict__ w1 /*32x33*/, const float* __restrict__ attl,
    const float* __restrict__ alsrc, const float* __restrict__ term,
    const bf16* __restrict__ ROWS, const float* __restrict__ bias,
    float* __restrict__ S,
    const float* __restrict__ wih, const float* __restrict__ whh,
    const float* __restrict__ bih, const float* __restrict__ bhh,
    const float* __restrict__ attW, const float* __restrict__ att1,
    const float* __restrict__ att2,
    bf16* __restrict__ xt, float* __restrict__ s1, float* __restrict__ s2){
  __shared__ float hl[64][33];
  int nb0 = (int)blockIdx.x * 64;
  // ---------- phase 1: conv ----------
  {
    int g = threadIdx.x >> 5;
    int c32 = threadIdx.x & 31;
    float wc[32], at[32];
    if (U){
      #pragma unroll
      for (int j = 0; j < 32; j++){ wc[j] = w1[j*33 + 32]; at[j] = attl[j]; }
    }
    int eg = c32 >> 2, cb = c32 & 3;
    for (int i = 0; i < 8; i++){
      int ln = g*8 + i;
      int node = nb0 + ln;
      int ws = rowptr[node], we = rowptr[node+1];
      float tv = term[node];
      float s = 0.f;
      float acc[8];
      #pragma unroll
      for (int j = 0; j < 8; j++) acc[j] = 0.f;
      for (int p0 = ws; p0 < we; p0 += 32){
        int p = p0 + c32;
        bool ok = p < we;
        int pc = ok ? p : ws;
        int2 pk = epk[pc];
        int siA = pk.x;
        float sc;
        if (U){
          float a = __int_as_float(pk.y);
          const short8v* ur = (const short8v*)(U + (size_t)siA*32);
          sc = 0.f;
          #pragma unroll
          for (int q = 0; q < 4; q++){
            short8v u8 = ur[q];
            #pragma unroll
            for (int j = 0; j < 8; j++)
              sc += at[q*8+j]*lrelu(s2f(u8[j]) + a*wc[q*8+j]);
          }
        } else {
          sc = alsrc[siA];
        }
        float wme = ok ? __expf(lrelu(sc + tv)) : 0.f;
        s += redsum32(wme);
        #pragma unroll
        for (int s8 = 0; s8 < 32; s8 += 8){
          if (p0 + s8 >= we) break;
          float w = __shfl(wme, s8 + eg, 32);
          int si  = __shfl(siA, s8 + eg, 32);
          short8v r8 = *(const short8v*)(ROWS + (size_t)si*32 + cb*8);
          #pragma unroll
          for (int j = 0; j < 8; j++) acc[j] += s2f(r8[j]) * w;
        }
      }
      float inv = 1.f/(s + 1e-16f);
      #pragma unroll
      for (int j = 0; j < 8; j++){
        acc[j] += __shfl_xor(acc[j], 4, 32);
        acc[j] += __shfl_xor(acc[j], 8, 32);
        acc[j] += __shfl_xor(acc[j], 16, 32);
      }
      if (eg == 0){
        #pragma unroll
        for (int j = 0; j < 8; j++)
          hl[ln][cb*8 + j] = eluf(acc[j]*inv + bias[cb*8 + j]);
      }
    }
  }
  __syncthreads();
  // ---------- phase 2: GRU (MFMA) + att precompute ----------
  {
    int wv   = threadIdx.x >> 6;        // wave 0..3 -> 16-node tile
    int lane = threadIdx.x & 63;
    int cl = lane & 15;
    int kb = lane >> 4;
    short8v BW[12], BT[2];
    #pragma unroll
    for (int g = 0; g < 6; g++){
      const float* wr = wih + (size_t)(g*16 + cl)*32 + kb*8;
      const float* vr = whh + (size_t)(g*16 + cl)*32 + kb*8;
      short8v bw, bv;
      #pragma unroll
      for (int j = 0; j < 8; j++){ bw[j] = (short)bfbits(wr[j]); bv[j] = (short)bfbits(vr[j]); }
      BW[g] = bw; BW[6+g] = bv;
    }
    #pragma unroll
    for (int g = 0; g < 2; g++){
      short8v bt;
      #pragma unroll
      for (int j = 0; j < 8; j++) bt[j] = (short)bfbits(attW[(size_t)(g*16+cl)*32 + kb*8 + j]);
      BT[g] = bt;
    }
    float bI[6], bH[6];
    #pragma unroll
    for (int g = 0; g < 6; g++){ bI[g] = bih[g*16 + cl]; bH[g] = bhh[g*16 + cl]; }
    float a1c0 = att1[cl], a1c1 = att1[16+cl];
    float a2c0 = att2 ? att2[cl] : 0.f, a2c1 = att2 ? att2[16+cl] : 0.f;
    f32x4 zero; zero[0]=0.f; zero[1]=0.f; zero[2]=0.f; zero[3]=0.f;

    int nb = nb0 + wv*16;
    short8v Ah;
    #pragma unroll
    for (int j = 0; j < 8; j++) Ah[j] = (short)bfbits(hl[wv*16 + cl][kb*8 + j]);
    const float* xr = S + (size_t)(nb + cl)*32 + kb*8;
    short8v Ax;
    #pragma unroll
    for (int j = 0; j < 8; j++) Ax[j] = (short)bfbits(xr[j]);
    f32x4 gi[6], gh[6];
    #pragma unroll
    for (int g = 0; g < 6; g++){
      f32x4 a, b;
      #pragma unroll
      for (int q = 0; q < 4; q++){ a[q] = bI[g]; b[q] = bH[g]; }
      gi[g] = __builtin_amdgcn_mfma_f32_16x16x32_bf16(Ah, BW[g],   a, 0, 0, 0);
      gh[g] = __builtin_amdgcn_mfma_f32_16x16x32_bf16(Ax, BW[6+g], b, 0, 0, 0);
    }
    #pragma unroll
    for (int r = 0; r < 4; r++){
      int node = nb + kb*4 + r;
      float* srow = S + (size_t)node*32;
      float x0 = srow[cl], x1 = srow[16 + cl];
      float r0 = sigm(gi[0][r] + gh[0][r]);
      float z0 = sigm(gi[2][r] + gh[2][r]);
      float n0 = tanh_fast(gi[4][r] + r0*gh[4][r]);
      float r1 = sigm(gi[1][r] + gh[1][r]);
      float z1 = sigm(gi[3][r] + gh[3][r]);
      float n1 = tanh_fast(gi[5][r] + r1*gh[5][r]);
      float o0 = fmaxf((1.f - z0)*n0 + z0*x0, 0.f);
      float o1 = fmaxf((1.f - z1)*n1 + z1*x1, 0.f);
      srow[cl]      = o0;
      srow[16 + cl] = o1;
      hl[wv*16 + kb*4 + r][cl]      = o0;   // intra-wave staging (Ah already consumed)
      hl[wv*16 + kb*4 + r][16 + cl] = o1;
    }
    short8v Ao;
    #pragma unroll
    for (int j = 0; j < 8; j++) Ao[j] = (short)bfbits(hl[wv*16 + cl][kb*8 + j]);
    f32x4 t0 = __builtin_amdgcn_mfma_f32_16x16x32_bf16(Ao, BT[0], zero, 0, 0, 0);
    f32x4 t1 = __builtin_amdgcn_mfma_f32_16x16x32_bf16(Ao, BT[1], zero, 0, 0, 0);
    #pragma unroll
    for (int r = 0; r < 4; r++){
      int node = nb + kb*4 + r;
      bf16* xrow = xt + (size_t)node*32;
      xrow[cl]      = f2b(t0[r]);
      xrow[16 + cl] = f2b(t1[r]);
      float p1 = t0[r]*a1c0 + t1[r]*a1c1;
      p1 += __shfl_xor(p1, 1, 16);
      p1 += __shfl_xor(p1, 2, 16);
      p1 += __shfl_xor(p1, 4, 16);
      p1 += __shfl_xor(p1, 8, 16);
      if (cl == 0) s1[node] = p1;
      if (att2){
        float p2 = t0[r]*a2c0 + t1[r]*a2c1;
        p2 += __shfl_xor(p2, 1, 16);
        p2 += __shfl_xor(p2, 2, 16);
        p2 += __shfl_xor(p2, 4, 16);
        p2 += __shfl_xor(p2, 8, 16);
        if (cl == 0) s2[node] = p2;
      }
    }
  }
}

// ======== fused readout: rsum + q + 2x(softmax+GRU3) + final mish ===========
// one 32-lane group per graph
__global__ __launch_bounds__(THREADS) void k_readout(const int* __restrict__ gptr,
    const float* __restrict__ X, const float* __restrict__ anode,
    const bf16* __restrict__ XS,
    const float* __restrict__ mw /*m_lin_w*/, const float* __restrict__ mattd,
    const float* __restrict__ mbias,
    const float* __restrict__ wih, const float* __restrict__ whh,
    const float* __restrict__ bih, const float* __restrict__ bhh,
    const float* __restrict__ lin2_w, const float* __restrict__ lin2_b,
    float* __restrict__ y){
  int g = blockIdx.x*(THREADS/32) + (threadIdx.x >> 5);
  int c = threadIdx.x & 31;
  int gs = gptr[g], ge = gptr[g+1];
  // rsum + relu
  float out = 0.f;
  for (int n = gs; n < ge; n++) out += X[(size_t)n*32 + c];
  out = fmaxf(out, 0.f);
  // q[c] = sum_j mattd[j] * mw[j*32 + c]
  float qc = 0.f;
  #pragma unroll
  for (int j = 0; j < 32; j++) qc += mattd[j]*mw[j*32 + c];
  // 2 timesteps
  #pragma unroll 1
  for (int t = 0; t < 2; t++){
    float ag = redsum32(out * qc);
    float s = 0.f;
    for (int p0 = gs; p0 < ge; p0 += 32){
      int p = p0 + c;
      float e = (p < ge) ? __expf(lrelu(anode[p] + ag)) : 0.f;
      s += redsum32(e);
    }
    float inv = 1.f/(s + 1e-16f);
    float acc = 0.f;
    int n = gs;
    for (; n + 4 <= ge; n += 4){
      float e0 = __expf(lrelu(anode[n]   + ag));
      float e1 = __expf(lrelu(anode[n+1] + ag));
      float e2 = __expf(lrelu(anode[n+2] + ag));
      float e3 = __expf(lrelu(anode[n+3] + ag));
      acc += b2f(XS[(size_t)(n  )*32 + c])*e0 + b2f(XS[(size_t)(n+1)*32 + c])*e1
           + b2f(XS[(size_t)(n+2)*32 + c])*e2 + b2f(XS[(size_t)(n+3)*32 + c])*e3;
    }
    for (; n < ge; n++)
      acc += b2f(XS[(size_t)n*32 + c]) * __expf(lrelu(anode[n] + ag));
    acc *= inv;
    float hv = eluf(acc + mbias[c]);
    out = gru_relu(hv, out, c, wih, whh, bih, bhh);
  }
  // final: y[g*64 + oc] = mish(out . lin2_w[oc] + b[oc]) for oc in 0..63
  #pragma unroll
  for (int oc2 = 0; oc2 < 2; oc2++){
    int oc = oc2*32 + c;
    float facc = lin2_b[oc];
    const float* wr = lin2_w + (size_t)oc*32;
    #pragma unroll 8
    for (int k = 0; k < 32; k++) facc += __shfl(out, k, 32) * wr[k];
    float sp = fmaxf(facc, 0.f) + log1pf(expf(-fabsf(facc)));  // precise (final output)
    y[(size_t)g*64 + oc] = facc * tanhf(sp);
  }
}

extern "C" void kernel_launch(void* const* d_in, const int* in_sizes, int n_in,
                              void* d_out, int out_size, void* d_ws, size_t ws_size,
                              hipStream_t stream){
  const float* x_in     = (const float*)d_in[0];
  const float* ea       = (const float*)d_in[1];
  const int*   ei       = (const int*)  d_in[2];
  const int*   batch    = (const int*)  d_in[3];
  const float* lin1_w   = (const float*)d_in[4];
  const float* lin1_b   = (const float*)d_in[5];
  const float* g_lin1_w = (const float*)d_in[6];
  const float* g_lin2_w = (const float*)d_in[7];
  const float* g_att_l  = (const float*)d_in[8];
  const float* g_att_r  = (const float*)d_in[9];
  const float* g_bias   = (const float*)d_in[10];
  const float* gru1_wih = (const float*)d_in[11];
  const float* gru1_whh = (const float*)d_in[12];
  const float* gru1_bih = (const float*)d_in[13];
  const float* gru1_bhh = (const float*)d_in[14];
  const float* a_lin_w  = (const float*)d_in[15];
  const float* a_att_src= (const float*)d_in[16];
  const float* a_att_dst= (const float*)d_in[17];
  const float* a_bias   = (const float*)d_in[18];
  const float* gru2_wih = (const float*)d_in[19];
  const float* gru2_whh = (const float*)d_in[20];
  const float* gru2_bih = (const float*)d_in[21];
  const float* gru2_bhh = (const float*)d_in[22];
  const float* m_lin_w  = (const float*)d_in[23];
  const float* m_att_src= (const float*)d_in[24];
  const float* m_att_dst= (const float*)d_in[25];
  const float* m_bias   = (const float*)d_in[26];
  const float* gru3_wih = (const float*)d_in[27];
  const float* gru3_whh = (const float*)d_in[28];
  const float* gru3_bih = (const float*)d_in[29];
  const float* gru3_bhh = (const float*)d_in[30];
  const float* lin2_w   = (const float*)d_in[31];
  const float* lin2_b   = (const float*)d_in[32];

  float* W = (float*)d_ws;
  float* X     = W;                      // NN*32 f32
  bf16*  BA    = (bf16*)(W + 8388608);   // NN*32 bf16 : u, then xs (after conv1)
  bf16*  BB    = (bf16*)(W + 12582912);  // NN*32 bf16 : v
  int2*  EPK   = (int2*) (W + 16777216); // NE x (src, ea-bits)
  int*   RP1   = (int*)  (W + 20971520); // NN partial scan (dead after k_mid)
  bf16*  BC    = (bf16*) (W + 20971520); // NN*32 bf16 : xt (written by conv_gru1)
  int*   RANK  = (int*)  (W + 23068672); // NE within-dst ranks
  int*   ROWPTR= (int*)  (W + 25165824); // NN+1 (pad)
  int*   HIST  = (int*)  (W + 25428032); // NN
  int*   BTOT  = (int*)  (W + 25690176); // 1024
  float* NS1   = W + 25691200;           // NN : nr, then a_node (after conv1)
  float* NS2   = W + 25953344;           // NN : (spare)
  int*   GPTR  = (int*)  (W + 26215488); // NG+1 (pad)
  float* NS3   = W + 26223744;           // NN : al (gru1 out)
  float* NS4   = W + 26485888;           // NN : ar (gru1 out)

  dim3 b(THREADS);
  const int gNode  = NN/THREADS;        // 1024
  const int gCG    = NN/64;             // 4096 : conv+gru blocks (64 nodes each)
  const int gRO    = NG/(THREADS/32);   // 1024 : readout (8 graphs/block)

  // zero HIST (must precede k_front's histrank section)
  k_filli<<<gNode, b, 0, stream>>>(HIST, 0, NN);

  // FRONT: embed (MFMA) ∥ histrank (atomics) ∥ gptr
  k_front<<<FB_EMBED + FB_HIST + FB_GPTR, b, 0, stream>>>(
      x_in, lin1_w, lin1_b, g_lin1_w, g_lin2_w, g_att_r, X, BA, BB, NS1,
      ei, HIST, RANK, batch, GPTR);

  // scans; MID: final rowptr ∥ atomic-free place
  k_scan1<<<gNode, b, 0, stream>>>(HIST, RP1, BTOT);
  k_scan2<<<1, 1024, 0, stream>>>(BTOT);
  k_mid<<<MB_SCAN + NE/THREADS, b, 0, stream>>>(RP1, BTOT, ROWPTR, ei, ea, RANK, EPK);

  // GATEConv (inline edge score from U=BA) + GRU1 + GATConv precompute
  //   reads: BA(u), BB(v), NS1(nr), X ; writes: X, BC(xt), NS3(al), NS4(ar)
  k_conv_gru<<<gCG, b, 0, stream>>>(ROWPTR, EPK, BA, g_lin1_w, g_att_l,
      nullptr, NS1, BB, g_bias, X,
      gru1_wih, gru1_whh, gru1_bih, gru1_bhh,
      a_lin_w, a_att_src, a_att_dst, BC, NS3, NS4);

  // GATConv (score = al[src]+ar[dst]) + GRU2 + readout precompute
  //   reads: BC(xt), NS3(al), NS4(ar), X ; writes: X, BA(xs), NS1(a_node)
  k_conv_gru<<<gCG, b, 0, stream>>>(ROWPTR, EPK, nullptr, nullptr, nullptr,
      NS3, NS4, BC, a_bias, X,
      gru2_wih, gru2_whh, gru2_bih, gru2_bhh,
      m_lin_w, m_att_src, nullptr, BA, NS1, nullptr);

  // fused readout: rsum + q + 2x(softmax+GRU3) + final mish
  k_readout<<<gRO, b, 0, stream>>>(GPTR, X, NS1, BA, m_lin_w, m_att_dst, m_bias,
      gru3_wih, gru3_whh, gru3_bih, gru3_bhh, lin2_w, lin2_b, (float*)d_out);
}

// Round 18
// 454.531 us; speedup vs baseline: 1.3171x; 1.3171x over previous
//
#include <hip/hip_runtime.h>
#include <hip/hip_bf16.h>
#include <math.h>

#define NN 262144
#define NE 2097152
#define NG 8192
#define THREADS 256

typedef __hip_bfloat16 bf16;
typedef __attribute__((ext_vector_type(8))) short short8v;   // 8 bf16 (4 VGPRs)
typedef __attribute__((ext_vector_type(4))) float f32x4;

static __device__ __forceinline__ float lrelu(float x){ return x > 0.f ? x : 0.01f*x; }
static __device__ __forceinline__ float eluf(float x){ return x > 0.f ? x : __expf(x) - 1.f; }
static __device__ __forceinline__ float sigm(float x){ return 1.f/(1.f + __expf(-x)); }
static __device__ __forceinline__ float tanh_fast(float x){
  float e = __expf(2.f*x); return 1.f - 2.f/(e + 1.f);
}
static __device__ __forceinline__ float b2f(bf16 v){ return __bfloat162float(v); }
static __device__ __forceinline__ bf16 f2b(float v){ return __float2bfloat16(v); }
// bit-reinterpret a raw bf16 (held in a short) to float — NEVER value-convert!
static __device__ __forceinline__ float s2f(short s){
  return __uint_as_float(((unsigned int)(unsigned short)s) << 16);
}

static __device__ __forceinline__ unsigned short bfbits(float f){
  union { bf16 b; unsigned short s; } u; u.b = f2b(f); return u.s;
}
static __device__ __forceinline__ unsigned int pack2(float lo, float hi){
  return (unsigned int)bfbits(lo) | ((unsigned int)bfbits(hi) << 16);
}

static __device__ __forceinline__ float redsum32(float t){
  #pragma unroll
  for (int o = 16; o > 0; o >>= 1) t += __shfl_xor(t, o, 32);
  return t;
}

// GRU helper for the readout kernel (32 lanes = one row)
static __device__ __forceinline__ float gru_relu(float hv, float xv, int c,
    const float* __restrict__ wih, const float* __restrict__ whh,
    const float* __restrict__ bih, const float* __restrict__ bhh){
  float gr = bih[c], gz = bih[32+c], gn = bih[64+c];
  float hr = bhh[c], hz = bhh[32+c], hn = bhh[64+c];
  #pragma unroll 8
  for (int k = 0; k < 32; k++){
    float hk = __shfl(hv, k, 32);
    float xk = __shfl(xv, k, 32);
    gr += hk*wih[(     c)*32 + k];
    gz += hk*wih[(32 + c)*32 + k];
    gn += hk*wih[(64 + c)*32 + k];
    hr += xk*whh[(     c)*32 + k];
    hz += xk*whh[(32 + c)*32 + k];
    hn += xk*whh[(64 + c)*32 + k];
  }
  float r = sigm(gr + hr), z = sigm(gz + hz);
  float nn2 = tanh_fast(gn + r*hn);
  return fmaxf((1.f - z)*nn2 + z*xv, 0.f);
}

__global__ __launch_bounds__(THREADS) void k_filli(int* __restrict__ p, int v, int n){
  int i = blockIdx.x*THREADS + threadIdx.x;
  if (i < n) p[i] = v;
}

// ================= FRONT mega-kernel: embed (MFMA) ∥ histrank ∥ gptr ==========
#define FB_EMBED 512
#define FB_HIST  8192
#define FB_GPTR  1024

__global__ __launch_bounds__(THREADS) void k_front(
    const float* __restrict__ xin, const float* __restrict__ lw, const float* __restrict__ lb,
    const float* __restrict__ w1, const float* __restrict__ w2,
    const float* __restrict__ attr_r, float* __restrict__ X,
    bf16* __restrict__ u, bf16* __restrict__ v, float* __restrict__ nr,
    const int* __restrict__ ei, int* __restrict__ hist, int* __restrict__ rank,
    const int* __restrict__ batch, int* __restrict__ gptr){
  __shared__ float ol[4][16][33];
  int bid = blockIdx.x;
  if (bid < FB_EMBED){
    int wid  = bid*4 + (threadIdx.x >> 6);
    int wv   = threadIdx.x >> 6;
    int lane = threadIdx.x & 63;
    int cl = lane & 15;
    int kb = lane >> 4;
    short8v BL[2][2], BU[2], BV[2];
    #pragma unroll
    for (int g = 0; g < 2; g++){
      #pragma unroll
      for (int kc = 0; kc < 2; kc++){
        short8v t;
        #pragma unroll
        for (int j = 0; j < 8; j++){
          int k = kc*32 + kb*8 + j;
          t[j] = (k < 54) ? (short)bfbits(lw[(size_t)(g*16+cl)*54 + k]) : (short)0;
        }
        BL[g][kc] = t;
      }
      short8v tu, tv;
      #pragma unroll
      for (int j = 0; j < 8; j++){
        tu[j] = (short)bfbits(w1[(size_t)(g*16+cl)*33 + kb*8 + j]);
        tv[j] = (short)bfbits(w2[(size_t)(g*16+cl)*32 + kb*8 + j]);
      }
      BU[g] = tu; BV[g] = tv;
    }
    float bb0 = lb[cl], bb1 = lb[16+cl];
    float ar0 = attr_r[cl], ar1 = attr_r[16+cl];
    f32x4 zero; zero[0]=0.f; zero[1]=0.f; zero[2]=0.f; zero[3]=0.f;

    for (int t = 0; t < 8; t++){
      int nb = (wid*8 + t)*16;
      const float* xrow = xin + (size_t)(nb + cl)*54;
      short8v Ax0, Ax1;
      const float2* x2 = (const float2*)(xrow + kb*8);
      #pragma unroll
      for (int jj = 0; jj < 4; jj++){
        float2 tvv = x2[jj];
        Ax0[2*jj]   = (short)bfbits(tvv.x);
        Ax0[2*jj+1] = (short)bfbits(tvv.y);
      }
      #pragma unroll
      for (int j = 0; j < 8; j++){
        int k = 32 + kb*8 + j;
        Ax1[j] = (k < 54) ? (short)bfbits(xrow[k]) : (short)0;
      }
      f32x4 a0, a1;
      #pragma unroll
      for (int q = 0; q < 4; q++){ a0[q] = bb0; a1[q] = bb1; }
      f32x4 d0 = __builtin_amdgcn_mfma_f32_16x16x32_bf16(Ax0, BL[0][0], a0, 0, 0, 0);
      d0 = __builtin_amdgcn_mfma_f32_16x16x32_bf16(Ax1, BL[0][1], d0, 0, 0, 0);
      f32x4 d1 = __builtin_amdgcn_mfma_f32_16x16x32_bf16(Ax0, BL[1][0], a1, 0, 0, 0);
      d1 = __builtin_amdgcn_mfma_f32_16x16x32_bf16(Ax1, BL[1][1], d1, 0, 0, 0);
      #pragma unroll
      for (int r = 0; r < 4; r++){ d0[r] = lrelu(d0[r]); d1[r] = lrelu(d1[r]); }
      #pragma unroll
      for (int r = 0; r < 4; r++){
        int node = nb + kb*4 + r;
        float* srow = X + (size_t)node*32;
        srow[cl]      = d0[r];
        srow[16 + cl] = d1[r];
        ol[wv][kb*4 + r][cl]      = d0[r];
        ol[wv][kb*4 + r][16 + cl] = d1[r];
      }
      #pragma unroll
      for (int r = 0; r < 4; r++){
        float vsum = d0[r]*ar0 + d1[r]*ar1;
        vsum += __shfl_xor(vsum, 1, 16);
        vsum += __shfl_xor(vsum, 2, 16);
        vsum += __shfl_xor(vsum, 4, 16);
        vsum += __shfl_xor(vsum, 8, 16);
        if (cl == 0) nr[nb + kb*4 + r] = vsum;
      }
      __syncthreads();
      short8v Ao;
      #pragma unroll
      for (int j = 0; j < 8; j++) Ao[j] = (short)bfbits(ol[wv][cl][kb*8 + j]);
      f32x4 u0 = __builtin_amdgcn_mfma_f32_16x16x32_bf16(Ao, BU[0], zero, 0, 0, 0);
      f32x4 u1 = __builtin_amdgcn_mfma_f32_16x16x32_bf16(Ao, BU[1], zero, 0, 0, 0);
      f32x4 v0 = __builtin_amdgcn_mfma_f32_16x16x32_bf16(Ao, BV[0], zero, 0, 0, 0);
      f32x4 v1 = __builtin_amdgcn_mfma_f32_16x16x32_bf16(Ao, BV[1], zero, 0, 0, 0);
      #pragma unroll
      for (int r = 0; r < 4; r++){
        int node = nb + kb*4 + r;
        bf16* ur = u + (size_t)node*32;
        bf16* vr = v + (size_t)node*32;
        ur[cl]      = f2b(u0[r]);
        ur[16 + cl] = f2b(u1[r]);
        vr[cl]      = f2b(v0[r]);
        vr[16 + cl] = f2b(v1[r]);
      }
      __syncthreads();
    }
  } else if (bid < FB_EMBED + FB_HIST){
    int e = (bid - FB_EMBED)*THREADS + threadIdx.x;
    rank[e] = atomicAdd(hist + ei[NE + e], 1);
  } else {
    int n = (bid - FB_EMBED - FB_HIST)*THREADS + threadIdx.x;
    int bc = batch[n];
    if (n == 0){ for (int g = 0; g <= bc; g++) gptr[g] = 0; }
    else {
      int pb = batch[n-1];
      if (pb != bc) for (int g = pb+1; g <= bc; g++) gptr[g] = n;
    }
    if (n == NN-1){ for (int g = bc+1; g <= NG; g++) gptr[g] = NN; }
  }
}

// ---------------- scans ----------------
__global__ __launch_bounds__(THREADS) void k_scan1(const int* __restrict__ hist,
    int* __restrict__ rp1, int* __restrict__ btot){
  __shared__ int sh[THREADS];
  int i = blockIdx.x*THREADS + threadIdx.x;
  int v = hist[i];
  sh[threadIdx.x] = v; __syncthreads();
  #pragma unroll
  for (int off = 1; off < THREADS; off <<= 1){
    int t = (threadIdx.x >= off) ? sh[threadIdx.x - off] : 0;
    __syncthreads(); sh[threadIdx.x] += t; __syncthreads();
  }
  rp1[i] = sh[threadIdx.x] - v;
  if (threadIdx.x == THREADS-1) btot[blockIdx.x] = sh[THREADS-1];
}

__global__ __launch_bounds__(1024) void k_scan2(int* __restrict__ btot){
  __shared__ int sh[1024];
  int i = threadIdx.x;
  int v = btot[i];
  sh[i] = v; __syncthreads();
  for (int off = 1; off < 1024; off <<= 1){
    int t = (i >= off) ? sh[i - off] : 0;
    __syncthreads(); sh[i] += t; __syncthreads();
  }
  btot[i] = sh[i] - v;  // exclusive
}

// ======== MID mega-kernel: final rowptr ∥ atomic-free place ==================
#define MB_SCAN 1024

__global__ __launch_bounds__(THREADS) void k_mid(const int* __restrict__ rp1,
    const int* __restrict__ btot, int* __restrict__ rowptr,
    const int* __restrict__ ei, const float* __restrict__ ea,
    const int* __restrict__ rank, int2* __restrict__ epk){
  int bid = blockIdx.x;
  if (bid < MB_SCAN){
    int i = bid*THREADS + threadIdx.x;
    rowptr[i] = rp1[i] + btot[i >> 8];
    if (i == 0) rowptr[NN] = NE;
  } else {
    int e = (bid - MB_SCAN)*THREADS + threadIdx.x;
    int d = ei[NE + e];
    int pos = rp1[d] + btot[d >> 8] + rank[e];
    epk[pos] = make_int2(ei[e], __float_as_int(ea[e]));
  }
}

// ---- GRU via MFMA + fused att precompute (round-16 proven form) ----
__global__ __launch_bounds__(THREADS) void k_gru_att(const bf16* __restrict__ HV,
    float* __restrict__ S,
    const float* __restrict__ wih, const float* __restrict__ whh,
    const float* __restrict__ bih, const float* __restrict__ bhh,
    const float* __restrict__ attW, const float* __restrict__ att1,
    const float* __restrict__ att2,
    bf16* __restrict__ xt, float* __restrict__ s1, float* __restrict__ s2){
  __shared__ float ol[4][16][33];
  int wid  = (blockIdx.x*THREADS + threadIdx.x) >> 6;
  int wv   = threadIdx.x >> 6;
  int lane = threadIdx.x & 63;
  int cl = lane & 15;
  int kb = lane >> 4;
  short8v BW[12], BT[2];
  #pragma unroll
  for (int g = 0; g < 6; g++){
    const float* wr = wih + (size_t)(g*16 + cl)*32 + kb*8;
    const float* vr = whh + (size_t)(g*16 + cl)*32 + kb*8;
    short8v bw, bv;
    #pragma unroll
    for (int j = 0; j < 8; j++){ bw[j] = (short)bfbits(wr[j]); bv[j] = (short)bfbits(vr[j]); }
    BW[g] = bw; BW[6+g] = bv;
  }
  #pragma unroll
  for (int g = 0; g < 2; g++){
    short8v bt;
    #pragma unroll
    for (int j = 0; j < 8; j++) bt[j] = (short)bfbits(attW[(size_t)(g*16+cl)*32 + kb*8 + j]);
    BT[g] = bt;
  }
  float bI[6], bH[6];
  #pragma unroll
  for (int g = 0; g < 6; g++){ bI[g] = bih[g*16 + cl]; bH[g] = bhh[g*16 + cl]; }
  float a1c0 = att1[cl], a1c1 = att1[16+cl];
  float a2c0 = att2 ? att2[cl] : 0.f, a2c1 = att2 ? att2[16+cl] : 0.f;
  f32x4 zero; zero[0]=0.f; zero[1]=0.f; zero[2]=0.f; zero[3]=0.f;

  for (int t = 0; t < 8; t++){
    int nb = (wid*8 + t) * 16;
    short8v Ah = *(const short8v*)(HV + (size_t)(nb + cl)*32 + kb*8);
    const float* xr = S + (size_t)(nb + cl)*32 + kb*8;
    short8v Ax;
    #pragma unroll
    for (int j = 0; j < 8; j++) Ax[j] = (short)bfbits(xr[j]);
    f32x4 gi[6], gh[6];
    #pragma unroll
    for (int g = 0; g < 6; g++){
      f32x4 a, b;
      #pragma unroll
      for (int q = 0; q < 4; q++){ a[q] = bI[g]; b[q] = bH[g]; }
      gi[g] = __builtin_amdgcn_mfma_f32_16x16x32_bf16(Ah, BW[g],   a, 0, 0, 0);
      gh[g] = __builtin_amdgcn_mfma_f32_16x16x32_bf16(Ax, BW[6+g], b, 0, 0, 0);
    }
    #pragma unroll
    for (int r = 0; r < 4; r++){
      int node = nb + kb*4 + r;
      float* srow = S + (size_t)node*32;
      float x0 = srow[cl], x1 = srow[16 + cl];
      float r0 = sigm(gi[0][r] + gh[0][r]);
      float z0 = sigm(gi[2][r] + gh[2][r]);
      float n0 = tanh_fast(gi[4][r] + r0*gh[4][r]);
      float r1 = sigm(gi[1][r] + gh[1][r]);
      float z1 = sigm(gi[3][r] + gh[3][r]);
      float n1 = tanh_fast(gi[5][r] + r1*gh[5][r]);
      float o0 = fmaxf((1.f - z0)*n0 + z0*x0, 0.f);
      float o1 = fmaxf((1.f - z1)*n1 + z1*x1, 0.f);
      srow[cl]      = o0;
      srow[16 + cl] = o1;
      ol[wv][kb*4 + r][cl]      = o0;
      ol[wv][kb*4 + r][16 + cl] = o1;
    }
    __syncthreads();
    short8v Ao;
    #pragma unroll
    for (int j = 0; j < 8; j++) Ao[j] = (short)bfbits(ol[wv][cl][kb*8 + j]);
    f32x4 t0 = __builtin_amdgcn_mfma_f32_16x16x32_bf16(Ao, BT[0], zero, 0, 0, 0);
    f32x4 t1 = __builtin_amdgcn_mfma_f32_16x16x32_bf16(Ao, BT[1], zero, 0, 0, 0);
    #pragma unroll
    for (int r = 0; r < 4; r++){
      int node = nb + kb*4 + r;
      bf16* xrow = xt + (size_t)node*32;
      xrow[cl]      = f2b(t0[r]);
      xrow[16 + cl] = f2b(t1[r]);
      float p1 = t0[r]*a1c0 + t1[r]*a1c1;
      p1 += __shfl_xor(p1, 1, 16);
      p1 += __shfl_xor(p1, 2, 16);
      p1 += __shfl_xor(p1, 4, 16);
      p1 += __shfl_xor(p1, 8, 16);
      if (cl == 0) s1[node] = p1;
      if (att2){
        float p2 = t0[r]*a2c0 + t1[r]*a2c1;
        p2 += __shfl_xor(p2, 1, 16);
        p2 += __shfl_xor(p2, 2, 16);
        p2 += __shfl_xor(p2, 4, 16);
        p2 += __shfl_xor(p2, 8, 16);
        if (cl == 0) s2[node] = p2;
      }
    }
    __syncthreads();
  }
}

// ---- conv v3 (round-16 proven): no-max softmax; inline GATE score or al gather ----
__global__ __launch_bounds__(THREADS) void k_conv(const int* __restrict__ rowptr,
    const int2* __restrict__ epk, const bf16* __restrict__ U,
    const float* __restrict__ w1 /*32x33*/, const float* __restrict__ attl,
    const float* __restrict__ alsrc, const float* __restrict__ term,
    const bf16* __restrict__ ROWS, const float* __restrict__ bias,
    bf16* __restrict__ HV){
  int node = blockIdx.x*(THREADS/32) + (threadIdx.x >> 5);
  int c32 = threadIdx.x & 31;
  int ws = rowptr[node], we = rowptr[node+1];
  float tv = term[node];
  float wc[32], at[32];
  if (U){
    #pragma unroll
    for (int j = 0; j < 32; j++){ wc[j] = w1[j*33 + 32]; at[j] = attl[j]; }
  }
  int eg = c32 >> 2, cb = c32 & 3;
  float s = 0.f;
  float acc[8];
  #pragma unroll
  for (int j = 0; j < 8; j++) acc[j] = 0.f;
  for (int p0 = ws; p0 < we; p0 += 32){
    int p = p0 + c32;
    bool ok = p < we;
    int pc = ok ? p : ws;
    int2 pk = epk[pc];
    int siA = pk.x;
    float sc;
    if (U){
      float a = __int_as_float(pk.y);
      const short8v* ur = (const short8v*)(U + (size_t)siA*32);
      sc = 0.f;
      #pragma unroll
      for (int q = 0; q < 4; q++){
        short8v u8 = ur[q];
        #pragma unroll
        for (int j = 0; j < 8; j++)
          sc += at[q*8+j]*lrelu(s2f(u8[j]) + a*wc[q*8+j]);
      }
    } else {
      sc = alsrc[siA];
    }
    float wme = ok ? __expf(lrelu(sc + tv)) : 0.f;
    s += redsum32(wme);
    #pragma unroll
    for (int s8 = 0; s8 < 32; s8 += 8){
      if (p0 + s8 >= we) break;
      float w = __shfl(wme, s8 + eg, 32);
      int si  = __shfl(siA, s8 + eg, 32);
      short8v r8 = *(const short8v*)(ROWS + (size_t)si*32 + cb*8);
      #pragma unroll
      for (int j = 0; j < 8; j++) acc[j] += s2f(r8[j]) * w;
    }
  }
  float inv = 1.f/(s + 1e-16f);
  #pragma unroll
  for (int j = 0; j < 8; j++){
    acc[j] += __shfl_xor(acc[j], 4, 32);
    acc[j] += __shfl_xor(acc[j], 8, 32);
    acc[j] += __shfl_xor(acc[j], 16, 32);
  }
  if (eg == 0){
    unsigned int o[4];
    #pragma unroll
    for (int j2 = 0; j2 < 4; j2++){
      float h0 = eluf(acc[2*j2  ]*inv + bias[cb*8 + 2*j2  ]);
      float h1 = eluf(acc[2*j2+1]*inv + bias[cb*8 + 2*j2+1]);
      o[j2] = pack2(h0, h1);
    }
    *(uint4*)(HV + (size_t)node*32 + cb*8) = make_uint4(o[0], o[1], o[2], o[3]);
  }
}

// ======== fused readout: rsum + q + 2x(softmax+GRU3) + final mish ===========
__global__ __launch_bounds__(THREADS) void k_readout(const int* __restrict__ gptr,
    const float* __restrict__ X, const float* __restrict__ anode,
    const bf16* __restrict__ XS,
    const float* __restrict__ mw /*m_lin_w*/, const float* __restrict__ mattd,
    const float* __restrict__ mbias,
    const float* __restrict__ wih, const float* __restrict__ whh,
    const float* __restrict__ bih, const float* __restrict__ bhh,
    const float* __restrict__ lin2_w, const float* __restrict__ lin2_b,
    float* __restrict__ y){
  int g = blockIdx.x*(THREADS/32) + (threadIdx.x >> 5);
  int c = threadIdx.x & 31;
  int gs = gptr[g], ge = gptr[g+1];
  // rsum + relu
  float out = 0.f;
  for (int n = gs; n < ge; n++) out += X[(size_t)n*32 + c];
  out = fmaxf(out, 0.f);
  // q[c]
  float qc = 0.f;
  #pragma unroll
  for (int j = 0; j < 32; j++) qc += mattd[j]*mw[j*32 + c];
  // 2 timesteps
  #pragma unroll 1
  for (int t = 0; t < 2; t++){
    float ag = redsum32(out * qc);
    float s = 0.f;
    for (int p0 = gs; p0 < ge; p0 += 32){
      int p = p0 + c;
      float e = (p < ge) ? __expf(lrelu(anode[p] + ag)) : 0.f;
      s += redsum32(e);
    }
    float inv = 1.f/(s + 1e-16f);
    float acc = 0.f;
    int n = gs;
    for (; n + 4 <= ge; n += 4){
      float e0 = __expf(lrelu(anode[n]   + ag));
      float e1 = __expf(lrelu(anode[n+1] + ag));
      float e2 = __expf(lrelu(anode[n+2] + ag));
      float e3 = __expf(lrelu(anode[n+3] + ag));
      acc += b2f(XS[(size_t)(n  )*32 + c])*e0 + b2f(XS[(size_t)(n+1)*32 + c])*e1
           + b2f(XS[(size_t)(n+2)*32 + c])*e2 + b2f(XS[(size_t)(n+3)*32 + c])*e3;
    }
    for (; n < ge; n++)
      acc += b2f(XS[(size_t)n*32 + c]) * __expf(lrelu(anode[n] + ag));
    acc *= inv;
    float hv = eluf(acc + mbias[c]);
    out = gru_relu(hv, out, c, wih, whh, bih, bhh);
  }
  // final: y = mish(out @ lin2^T + b)
  #pragma unroll
  for (int oc2 = 0; oc2 < 2; oc2++){
    int oc = oc2*32 + c;
    float facc = lin2_b[oc];
    const float* wr = lin2_w + (size_t)oc*32;
    #pragma unroll 8
    for (int k = 0; k < 32; k++) facc += __shfl(out, k, 32) * wr[k];
    float sp = fmaxf(facc, 0.f) + log1pf(expf(-fabsf(facc)));  // precise (final output)
    y[(size_t)g*64 + oc] = facc * tanhf(sp);
  }
}

extern "C" void kernel_launch(void* const* d_in, const int* in_sizes, int n_in,
                              void* d_out, int out_size, void* d_ws, size_t ws_size,
                              hipStream_t stream){
  const float* x_in     = (const float*)d_in[0];
  const float* ea       = (const float*)d_in[1];
  const int*   ei       = (const int*)  d_in[2];
  const int*   batch    = (const int*)  d_in[3];
  const float* lin1_w   = (const float*)d_in[4];
  const float* lin1_b   = (const float*)d_in[5];
  const float* g_lin1_w = (const float*)d_in[6];
  const float* g_lin2_w = (const float*)d_in[7];
  const float* g_att_l  = (const float*)d_in[8];
  const float* g_att_r  = (const float*)d_in[9];
  const float* g_bias   = (const float*)d_in[10];
  const float* gru1_wih = (const float*)d_in[11];
  const float* gru1_whh = (const float*)d_in[12];
  const float* gru1_bih = (const float*)d_in[13];
  const float* gru1_bhh = (const float*)d_in[14];
  const float* a_lin_w  = (const float*)d_in[15];
  const float* a_att_src= (const float*)d_in[16];
  const float* a_att_dst= (const float*)d_in[17];
  const float* a_bias   = (const float*)d_in[18];
  const float* gru2_wih = (const float*)d_in[19];
  const float* gru2_whh = (const float*)d_in[20];
  const float* gru2_bih = (const float*)d_in[21];
  const float* gru2_bhh = (const float*)d_in[22];
  const float* m_lin_w  = (const float*)d_in[23];
  const float* m_att_src= (const float*)d_in[24];
  const float* m_att_dst= (const float*)d_in[25];
  const float* m_bias   = (const float*)d_in[26];
  const float* gru3_wih = (const float*)d_in[27];
  const float* gru3_whh = (const float*)d_in[28];
  const float* gru3_bih = (const float*)d_in[29];
  const float* gru3_bhh = (const float*)d_in[30];
  const float* lin2_w   = (const float*)d_in[31];
  const float* lin2_b   = (const float*)d_in[32];

  float* W = (float*)d_ws;
  float* X     = W;                      // NN*32 f32
  bf16*  BA    = (bf16*)(W + 8388608);   // NN*32 bf16 : u / xt / xs
  bf16*  BB    = (bf16*)(W + 12582912);  // NN*32 bf16 : v / h2
  int2*  EPK   = (int2*) (W + 16777216); // NE x (src, ea-bits)
  int*   RP1   = (int*)  (W + 20971520); // NN partial scan (dead after k_mid)
  bf16*  BC    = (bf16*) (W + 20971520); // NN*32 bf16 : h1 (after mid)
  int*   RANK  = (int*)  (W + 23068672); // NE within-dst ranks
  int*   ROWPTR= (int*)  (W + 25165824); // NN+1 (pad)
  int*   HIST  = (int*)  (W + 25428032); // NN
  int*   BTOT  = (int*)  (W + 25690176); // 1024
  float* NS1   = W + 25691200;           // NN : nr / al / a_node
  float* NS2   = W + 25953344;           // NN : ar
  int*   GPTR  = (int*)  (W + 26215488); // NG+1 (pad)

  dim3 b(THREADS);
  const int gNode  = NN/THREADS;        // 1024
  const int gNode32= NN/(THREADS/32);   // 32768
  const int gMFMA  = NN/(16*8*4);       // 512
  const int gRO    = NG/(THREADS/32);   // 1024

  // zero HIST (must precede k_front's histrank section)
  k_filli<<<gNode, b, 0, stream>>>(HIST, 0, NN);

  // FRONT: embed (MFMA) ∥ histrank (atomics) ∥ gptr
  k_front<<<FB_EMBED + FB_HIST + FB_GPTR, b, 0, stream>>>(
      x_in, lin1_w, lin1_b, g_lin1_w, g_lin2_w, g_att_r, X, BA, BB, NS1,
      ei, HIST, RANK, batch, GPTR);

  // scans; MID: final rowptr ∥ atomic-free place
  k_scan1<<<gNode, b, 0, stream>>>(HIST, RP1, BTOT);
  k_scan2<<<1, 1024, 0, stream>>>(BTOT);
  k_mid<<<MB_SCAN + NE/THREADS, b, 0, stream>>>(RP1, BTOT, ROWPTR, ei, ea, RANK, EPK);

  // GATEConv (inline edge score) + GRU1 (fused GATConv precompute)
  k_conv<<<gNode32, b, 0, stream>>>(ROWPTR, EPK, BA, g_lin1_w, g_att_l,
      nullptr, NS1, BB, g_bias, BC);
  k_gru_att<<<gMFMA, b, 0, stream>>>(BC, X, gru1_wih, gru1_whh, gru1_bih, gru1_bhh,
      a_lin_w, a_att_src, a_att_dst, BA, NS1, NS2);

  // GATConv + GRU2 (fused readout precompute)
  k_conv<<<gNode32, b, 0, stream>>>(ROWPTR, EPK, nullptr, nullptr, nullptr,
      NS1, NS2, BA, a_bias, BB);
  k_gru_att<<<gMFMA, b, 0, stream>>>(BB, X, gru2_wih, gru2_whh, gru2_bih, gru2_bhh,
      m_lin_w, m_att_src, nullptr, BA, NS1, nullptr);

  // fused readout: rsum + q + 2x(softmax+GRU3) + final mish
  k_readout<<<gRO, b, 0, stream>>>(GPTR, X, NS1, BA, m_lin_w, m_att_dst, m_bias,
      gru3_wih, gru3_whh, gru3_bih, gru3_bhh, lin2_w, lin2_b, (float*)d_out);
}

// Round 19
// 451.011 us; speedup vs baseline: 1.3274x; 1.0078x over previous
//
#include <hip/hip_runtime.h>
#include <hip/hip_bf16.h>
#include <math.h>

#define NN 262144
#define NE 2097152
#define NG 8192
#define THREADS 256

typedef __hip_bfloat16 bf16;
typedef __attribute__((ext_vector_type(8))) short short8v;   // 8 bf16 (4 VGPRs)
typedef __attribute__((ext_vector_type(4))) float f32x4;

static __device__ __forceinline__ float lrelu(float x){ return x > 0.f ? x : 0.01f*x; }
static __device__ __forceinline__ float eluf(float x){ return x > 0.f ? x : __expf(x) - 1.f; }
static __device__ __forceinline__ float sigm(float x){ return 1.f/(1.f + __expf(-x)); }
static __device__ __forceinline__ float tanh_fast(float x){
  float e = __expf(2.f*x); return 1.f - 2.f/(e + 1.f);
}
static __device__ __forceinline__ float b2f(bf16 v){ return __bfloat162float(v); }
static __device__ __forceinline__ bf16 f2b(float v){ return __float2bfloat16(v); }
// bit-reinterpret a raw bf16 (held in a short) to float — NEVER value-convert!
static __device__ __forceinline__ float s2f(short s){
  return __uint_as_float(((unsigned int)(unsigned short)s) << 16);
}

static __device__ __forceinline__ unsigned short bfbits(float f){
  union { bf16 b; unsigned short s; } u; u.b = f2b(f); return u.s;
}
static __device__ __forceinline__ unsigned int pack2(float lo, float hi){
  return (unsigned int)bfbits(lo) | ((unsigned int)bfbits(hi) << 16);
}

static __device__ __forceinline__ float redsum32(float t){
  #pragma unroll
  for (int o = 16; o > 0; o >>= 1) t += __shfl_xor(t, o, 32);
  return t;
}

// GRU helper for the readout kernel (32 lanes = one row)
static __device__ __forceinline__ float gru_relu(float hv, float xv, int c,
    const float* __restrict__ wih, const float* __restrict__ whh,
    const float* __restrict__ bih, const float* __restrict__ bhh){
  float gr = bih[c], gz = bih[32+c], gn = bih[64+c];
  float hr = bhh[c], hz = bhh[32+c], hn = bhh[64+c];
  #pragma unroll 8
  for (int k = 0; k < 32; k++){
    float hk = __shfl(hv, k, 32);
    float xk = __shfl(xv, k, 32);
    gr += hk*wih[(     c)*32 + k];
    gz += hk*wih[(32 + c)*32 + k];
    gn += hk*wih[(64 + c)*32 + k];
    hr += xk*whh[(     c)*32 + k];
    hz += xk*whh[(32 + c)*32 + k];
    hn += xk*whh[(64 + c)*32 + k];
  }
  float r = sigm(gr + hr), z = sigm(gz + hz);
  float nn2 = tanh_fast(gn + r*hn);
  return fmaxf((1.f - z)*nn2 + z*xv, 0.f);
}

__global__ __launch_bounds__(THREADS) void k_filli(int* __restrict__ p, int v, int n){
  int i = blockIdx.x*THREADS + threadIdx.x;
  if (i < n) p[i] = v;
}

// ================= FRONT mega-kernel: embed (MFMA) ∥ histrank ∥ gptr ==========
// embed writes u/v INTERLEAVED: uv[node*64 + 0..31] = u row, +32..63 = v row.
#define FB_EMBED 512
#define FB_HIST  8192
#define FB_GPTR  1024

__global__ __launch_bounds__(THREADS) void k_front(
    const float* __restrict__ xin, const float* __restrict__ lw, const float* __restrict__ lb,
    const float* __restrict__ w1, const float* __restrict__ w2,
    const float* __restrict__ attr_r, float* __restrict__ X,
    bf16* __restrict__ uv, float* __restrict__ nr,
    const int* __restrict__ ei, int* __restrict__ hist, int* __restrict__ rank,
    const int* __restrict__ batch, int* __restrict__ gptr){
  __shared__ float ol[4][16][33];
  int bid = blockIdx.x;
  if (bid < FB_EMBED){
    int wid  = bid*4 + (threadIdx.x >> 6);
    int wv   = threadIdx.x >> 6;
    int lane = threadIdx.x & 63;
    int cl = lane & 15;
    int kb = lane >> 4;
    short8v BL[2][2], BU[2], BV[2];
    #pragma unroll
    for (int g = 0; g < 2; g++){
      #pragma unroll
      for (int kc = 0; kc < 2; kc++){
        short8v t;
        #pragma unroll
        for (int j = 0; j < 8; j++){
          int k = kc*32 + kb*8 + j;
          t[j] = (k < 54) ? (short)bfbits(lw[(size_t)(g*16+cl)*54 + k]) : (short)0;
        }
        BL[g][kc] = t;
      }
      short8v tu, tv;
      #pragma unroll
      for (int j = 0; j < 8; j++){
        tu[j] = (short)bfbits(w1[(size_t)(g*16+cl)*33 + kb*8 + j]);
        tv[j] = (short)bfbits(w2[(size_t)(g*16+cl)*32 + kb*8 + j]);
      }
      BU[g] = tu; BV[g] = tv;
    }
    float bb0 = lb[cl], bb1 = lb[16+cl];
    float ar0 = attr_r[cl], ar1 = attr_r[16+cl];
    f32x4 zero; zero[0]=0.f; zero[1]=0.f; zero[2]=0.f; zero[3]=0.f;

    for (int t = 0; t < 8; t++){
      int nb = (wid*8 + t)*16;
      const float* xrow = xin + (size_t)(nb + cl)*54;
      short8v Ax0, Ax1;
      const float2* x2 = (const float2*)(xrow + kb*8);
      #pragma unroll
      for (int jj = 0; jj < 4; jj++){
        float2 tvv = x2[jj];
        Ax0[2*jj]   = (short)bfbits(tvv.x);
        Ax0[2*jj+1] = (short)bfbits(tvv.y);
      }
      #pragma unroll
      for (int j = 0; j < 8; j++){
        int k = 32 + kb*8 + j;
        Ax1[j] = (k < 54) ? (short)bfbits(xrow[k]) : (short)0;
      }
      f32x4 a0, a1;
      #pragma unroll
      for (int q = 0; q < 4; q++){ a0[q] = bb0; a1[q] = bb1; }
      f32x4 d0 = __builtin_amdgcn_mfma_f32_16x16x32_bf16(Ax0, BL[0][0], a0, 0, 0, 0);
      d0 = __builtin_amdgcn_mfma_f32_16x16x32_bf16(Ax1, BL[0][1], d0, 0, 0, 0);
      f32x4 d1 = __builtin_amdgcn_mfma_f32_16x16x32_bf16(Ax0, BL[1][0], a1, 0, 0, 0);
      d1 = __builtin_amdgcn_mfma_f32_16x16x32_bf16(Ax1, BL[1][1], d1, 0, 0, 0);
      #pragma unroll
      for (int r = 0; r < 4; r++){ d0[r] = lrelu(d0[r]); d1[r] = lrelu(d1[r]); }
      #pragma unroll
      for (int r = 0; r < 4; r++){
        int node = nb + kb*4 + r;
        float* srow = X + (size_t)node*32;
        srow[cl]      = d0[r];
        srow[16 + cl] = d1[r];
        ol[wv][kb*4 + r][cl]      = d0[r];
        ol[wv][kb*4 + r][16 + cl] = d1[r];
      }
      #pragma unroll
      for (int r = 0; r < 4; r++){
        float vsum = d0[r]*ar0 + d1[r]*ar1;
        vsum += __shfl_xor(vsum, 1, 16);
        vsum += __shfl_xor(vsum, 2, 16);
        vsum += __shfl_xor(vsum, 4, 16);
        vsum += __shfl_xor(vsum, 8, 16);
        if (cl == 0) nr[nb + kb*4 + r] = vsum;
      }
      __syncthreads();
      short8v Ao;
      #pragma unroll
      for (int j = 0; j < 8; j++) Ao[j] = (short)bfbits(ol[wv][cl][kb*8 + j]);
      f32x4 u0 = __builtin_amdgcn_mfma_f32_16x16x32_bf16(Ao, BU[0], zero, 0, 0, 0);
      f32x4 u1 = __builtin_amdgcn_mfma_f32_16x16x32_bf16(Ao, BU[1], zero, 0, 0, 0);
      f32x4 v0 = __builtin_amdgcn_mfma_f32_16x16x32_bf16(Ao, BV[0], zero, 0, 0, 0);
      f32x4 v1 = __builtin_amdgcn_mfma_f32_16x16x32_bf16(Ao, BV[1], zero, 0, 0, 0);
      #pragma unroll
      for (int r = 0; r < 4; r++){
        int node = nb + kb*4 + r;
        bf16* rowp = uv + (size_t)node*64;     // interleaved u|v row (128B)
        rowp[cl]           = f2b(u0[r]);
        rowp[16 + cl]      = f2b(u1[r]);
        rowp[32 + cl]      = f2b(v0[r]);
        rowp[48 + cl]      = f2b(v1[r]);
      }
      __syncthreads();
    }
  } else if (bid < FB_EMBED + FB_HIST){
    int e = (bid - FB_EMBED)*THREADS + threadIdx.x;
    rank[e] = atomicAdd(hist + ei[NE + e], 1);
  } else {
    int n = (bid - FB_EMBED - FB_HIST)*THREADS + threadIdx.x;
    int bc = batch[n];
    if (n == 0){ for (int g = 0; g <= bc; g++) gptr[g] = 0; }
    else {
      int pb = batch[n-1];
      if (pb != bc) for (int g = pb+1; g <= bc; g++) gptr[g] = n;
    }
    if (n == NN-1){ for (int g = bc+1; g <= NG; g++) gptr[g] = NN; }
  }
}

// ---------------- scans ----------------
__global__ __launch_bounds__(THREADS) void k_scan1(const int* __restrict__ hist,
    int* __restrict__ rp1, int* __restrict__ btot){
  __shared__ int sh[THREADS];
  int i = blockIdx.x*THREADS + threadIdx.x;
  int v = hist[i];
  sh[threadIdx.x] = v; __syncthreads();
  #pragma unroll
  for (int off = 1; off < THREADS; off <<= 1){
    int t = (threadIdx.x >= off) ? sh[threadIdx.x - off] : 0;
    __syncthreads(); sh[threadIdx.x] += t; __syncthreads();
  }
  rp1[i] = sh[threadIdx.x] - v;
  if (threadIdx.x == THREADS-1) btot[blockIdx.x] = sh[THREADS-1];
}

__global__ __launch_bounds__(1024) void k_scan2(int* __restrict__ btot){
  __shared__ int sh[1024];
  int i = threadIdx.x;
  int v = btot[i];
  sh[i] = v; __syncthreads();
  for (int off = 1; off < 1024; off <<= 1){
    int t = (i >= off) ? sh[i - off] : 0;
    __syncthreads(); sh[i] += t; __syncthreads();
  }
  btot[i] = sh[i] - v;  // exclusive
}

// ======== MID mega-kernel: final rowptr ∥ atomic-free place ==================
#define MB_SCAN 1024

__global__ __launch_bounds__(THREADS) void k_mid(const int* __restrict__ rp1,
    const int* __restrict__ btot, int* __restrict__ rowptr,
    const int* __restrict__ ei, const float* __restrict__ ea,
    const int* __restrict__ rank, int2* __restrict__ epk){
  int bid = blockIdx.x;
  if (bid < MB_SCAN){
    int i = bid*THREADS + threadIdx.x;
    rowptr[i] = rp1[i] + btot[i >> 8];
    if (i == 0) rowptr[NN] = NE;
  } else {
    int e = (bid - MB_SCAN)*THREADS + threadIdx.x;
    int d = ei[NE + e];
    int pos = rp1[d] + btot[d >> 8] + rank[e];
    epk[pos] = make_int2(ei[e], __float_as_int(ea[e]));
  }
}

// ---- GRU via MFMA + fused att precompute (proven form) ----
__global__ __launch_bounds__(THREADS) void k_gru_att(const bf16* __restrict__ HV,
    float* __restrict__ S,
    const float* __restrict__ wih, const float* __restrict__ whh,
    const float* __restrict__ bih, const float* __restrict__ bhh,
    const float* __restrict__ attW, const float* __restrict__ att1,
    const float* __restrict__ att2,
    bf16* __restrict__ xt, float* __restrict__ s1, float* __restrict__ s2){
  __shared__ float ol[4][16][33];
  int wid  = (blockIdx.x*THREADS + threadIdx.x) >> 6;
  int wv   = threadIdx.x >> 6;
  int lane = threadIdx.x & 63;
  int cl = lane & 15;
  int kb = lane >> 4;
  short8v BW[12], BT[2];
  #pragma unroll
  for (int g = 0; g < 6; g++){
    const float* wr = wih + (size_t)(g*16 + cl)*32 + kb*8;
    const float* vr = whh + (size_t)(g*16 + cl)*32 + kb*8;
    short8v bw, bv;
    #pragma unroll
    for (int j = 0; j < 8; j++){ bw[j] = (short)bfbits(wr[j]); bv[j] = (short)bfbits(vr[j]); }
    BW[g] = bw; BW[6+g] = bv;
  }
  #pragma unroll
  for (int g = 0; g < 2; g++){
    short8v bt;
    #pragma unroll
    for (int j = 0; j < 8; j++) bt[j] = (short)bfbits(attW[(size_t)(g*16+cl)*32 + kb*8 + j]);
    BT[g] = bt;
  }
  float bI[6], bH[6];
  #pragma unroll
  for (int g = 0; g < 6; g++){ bI[g] = bih[g*16 + cl]; bH[g] = bhh[g*16 + cl]; }
  float a1c0 = att1[cl], a1c1 = att1[16+cl];
  float a2c0 = att2 ? att2[cl] : 0.f, a2c1 = att2 ? att2[16+cl] : 0.f;
  f32x4 zero; zero[0]=0.f; zero[1]=0.f; zero[2]=0.f; zero[3]=0.f;

  for (int t = 0; t < 8; t++){
    int nb = (wid*8 + t) * 16;
    short8v Ah = *(const short8v*)(HV + (size_t)(nb + cl)*32 + kb*8);
    const float* xr = S + (size_t)(nb + cl)*32 + kb*8;
    short8v Ax;
    #pragma unroll
    for (int j = 0; j < 8; j++) Ax[j] = (short)bfbits(xr[j]);
    f32x4 gi[6], gh[6];
    #pragma unroll
    for (int g = 0; g < 6; g++){
      f32x4 a, b;
      #pragma unroll
      for (int q = 0; q < 4; q++){ a[q] = bI[g]; b[q] = bH[g]; }
      gi[g] = __builtin_amdgcn_mfma_f32_16x16x32_bf16(Ah, BW[g],   a, 0, 0, 0);
      gh[g] = __builtin_amdgcn_mfma_f32_16x16x32_bf16(Ax, BW[6+g], b, 0, 0, 0);
    }
    #pragma unroll
    for (int r = 0; r < 4; r++){
      int node = nb + kb*4 + r;
      float* srow = S + (size_t)node*32;
      float x0 = srow[cl], x1 = srow[16 + cl];
      float r0 = sigm(gi[0][r] + gh[0][r]);
      float z0 = sigm(gi[2][r] + gh[2][r]);
      float n0 = tanh_fast(gi[4][r] + r0*gh[4][r]);
      float r1 = sigm(gi[1][r] + gh[1][r]);
      float z1 = sigm(gi[3][r] + gh[3][r]);
      float n1 = tanh_fast(gi[5][r] + r1*gh[5][r]);
      float o0 = fmaxf((1.f - z0)*n0 + z0*x0, 0.f);
      float o1 = fmaxf((1.f - z1)*n1 + z1*x1, 0.f);
      srow[cl]      = o0;
      srow[16 + cl] = o1;
      ol[wv][kb*4 + r][cl]      = o0;
      ol[wv][kb*4 + r][16 + cl] = o1;
    }
    __syncthreads();
    short8v Ao;
    #pragma unroll
    for (int j = 0; j < 8; j++) Ao[j] = (short)bfbits(ol[wv][cl][kb*8 + j]);
    f32x4 t0 = __builtin_amdgcn_mfma_f32_16x16x32_bf16(Ao, BT[0], zero, 0, 0, 0);
    f32x4 t1 = __builtin_amdgcn_mfma_f32_16x16x32_bf16(Ao, BT[1], zero, 0, 0, 0);
    #pragma unroll
    for (int r = 0; r < 4; r++){
      int node = nb + kb*4 + r;
      bf16* xrow = xt + (size_t)node*32;
      xrow[cl]      = f2b(t0[r]);
      xrow[16 + cl] = f2b(t1[r]);
      float p1 = t0[r]*a1c0 + t1[r]*a1c1;
      p1 += __shfl_xor(p1, 1, 16);
      p1 += __shfl_xor(p1, 2, 16);
      p1 += __shfl_xor(p1, 4, 16);
      p1 += __shfl_xor(p1, 8, 16);
      if (cl == 0) s1[node] = p1;
      if (att2){
        float p2 = t0[r]*a2c0 + t1[r]*a2c1;
        p2 += __shfl_xor(p2, 1, 16);
        p2 += __shfl_xor(p2, 2, 16);
        p2 += __shfl_xor(p2, 4, 16);
        p2 += __shfl_xor(p2, 8, 16);
        if (cl == 0) s2[node] = p2;
      }
    }
    __syncthreads();
  }
}

// ---- conv v4: no-max softmax; inline GATE score (U stride 64) or al gather.
// Gather rows at ROWS + si*rstride + voff (conv1: UV interleaved; conv2: linear xt).
__global__ __launch_bounds__(THREADS) void k_conv(const int* __restrict__ rowptr,
    const int2* __restrict__ epk, const bf16* __restrict__ U,
    const float* __restrict__ w1 /*32x33*/, const float* __restrict__ attl,
    const float* __restrict__ alsrc, const float* __restrict__ term,
    const bf16* __restrict__ ROWS, int rstride, int voff,
    const float* __restrict__ bias, bf16* __restrict__ HV){
  int node = blockIdx.x*(THREADS/32) + (threadIdx.x >> 5);
  int c32 = threadIdx.x & 31;
  int ws = rowptr[node], we = rowptr[node+1];
  float tv = term[node];
  float wc[32], at[32];
  if (U){
    #pragma unroll
    for (int j = 0; j < 32; j++){ wc[j] = w1[j*33 + 32]; at[j] = attl[j]; }
  }
  int eg = c32 >> 2, cb = c32 & 3;
  float s = 0.f;
  float acc[8];
  #pragma unroll
  for (int j = 0; j < 8; j++) acc[j] = 0.f;
  for (int p0 = ws; p0 < we; p0 += 32){
    int p = p0 + c32;
    bool ok = p < we;
    int pc = ok ? p : ws;
    int2 pk = epk[pc];
    int siA = pk.x;
    float sc;
    if (U){
      float a = __int_as_float(pk.y);
      const short8v* ur = (const short8v*)(U + (size_t)siA*64);  // u-half of UV row
      sc = 0.f;
      #pragma unroll
      for (int q = 0; q < 4; q++){
        short8v u8 = ur[q];
        #pragma unroll
        for (int j = 0; j < 8; j++)
          sc += at[q*8+j]*lrelu(s2f(u8[j]) + a*wc[q*8+j]);
      }
    } else {
      sc = alsrc[siA];
    }
    float wme = ok ? __expf(lrelu(sc + tv)) : 0.f;
    s += redsum32(wme);
    #pragma unroll
    for (int s8 = 0; s8 < 32; s8 += 8){
      if (p0 + s8 >= we) break;
      float w = __shfl(wme, s8 + eg, 32);
      int si  = __shfl(siA, s8 + eg, 32);
      short8v r8 = *(const short8v*)(ROWS + (size_t)si*rstride + voff + cb*8);
      #pragma unroll
      for (int j = 0; j < 8; j++) acc[j] += s2f(r8[j]) * w;
    }
  }
  float inv = 1.f/(s + 1e-16f);
  #pragma unroll
  for (int j = 0; j < 8; j++){
    acc[j] += __shfl_xor(acc[j], 4, 32);
    acc[j] += __shfl_xor(acc[j], 8, 32);
    acc[j] += __shfl_xor(acc[j], 16, 32);
  }
  if (eg == 0){
    unsigned int o[4];
    #pragma unroll
    for (int j2 = 0; j2 < 4; j2++){
      float h0 = eluf(acc[2*j2  ]*inv + bias[cb*8 + 2*j2  ]);
      float h1 = eluf(acc[2*j2+1]*inv + bias[cb*8 + 2*j2+1]);
      o[j2] = pack2(h0, h1);
    }
    *(uint4*)(HV + (size_t)node*32 + cb*8) = make_uint4(o[0], o[1], o[2], o[3]);
  }
}

// ======== fused readout: rsum + q + 2x(softmax+GRU3) + final mish ===========
__global__ __launch_bounds__(THREADS) void k_readout(const int* __restrict__ gptr,
    const float* __restrict__ X, const float* __restrict__ anode,
    const bf16* __restrict__ XS,
    const float* __restrict__ mw /*m_lin_w*/, const float* __restrict__ mattd,
    const float* __restrict__ mbias,
    const float* __restrict__ wih, const float* __restrict__ whh,
    const float* __restrict__ bih, const float* __restrict__ bhh,
    const float* __restrict__ lin2_w, const float* __restrict__ lin2_b,
    float* __restrict__ y){
  int g = blockIdx.x*(THREADS/32) + (threadIdx.x >> 5);
  int c = threadIdx.x & 31;
  int gs = gptr[g], ge = gptr[g+1];
  // rsum + relu
  float out = 0.f;
  for (int n = gs; n < ge; n++) out += X[(size_t)n*32 + c];
  out = fmaxf(out, 0.f);
  // q[c]
  float qc = 0.f;
  #pragma unroll
  for (int j = 0; j < 32; j++) qc += mattd[j]*mw[j*32 + c];
  // 2 timesteps
  #pragma unroll 1
  for (int t = 0; t < 2; t++){
    float ag = redsum32(out * qc);
    float s = 0.f;
    for (int p0 = gs; p0 < ge; p0 += 32){
      int p = p0 + c;
      float e = (p < ge) ? __expf(lrelu(anode[p] + ag)) : 0.f;
      s += redsum32(e);
    }
    float inv = 1.f/(s + 1e-16f);
    float acc = 0.f;
    int n = gs;
    for (; n + 4 <= ge; n += 4){
      float e0 = __expf(lrelu(anode[n]   + ag));
      float e1 = __expf(lrelu(anode[n+1] + ag));
      float e2 = __expf(lrelu(anode[n+2] + ag));
      float e3 = __expf(lrelu(anode[n+3] + ag));
      acc += b2f(XS[(size_t)(n  )*32 + c])*e0 + b2f(XS[(size_t)(n+1)*32 + c])*e1
           + b2f(XS[(size_t)(n+2)*32 + c])*e2 + b2f(XS[(size_t)(n+3)*32 + c])*e3;
    }
    for (; n < ge; n++)
      acc += b2f(XS[(size_t)n*32 + c]) * __expf(lrelu(anode[n] + ag));
    acc *= inv;
    float hv = eluf(acc + mbias[c]);
    out = gru_relu(hv, out, c, wih, whh, bih, bhh);
  }
  // final: y = mish(out @ lin2^T + b)
  #pragma unroll
  for (int oc2 = 0; oc2 < 2; oc2++){
    int oc = oc2*32 + c;
    float facc = lin2_b[oc];
    const float* wr = lin2_w + (size_t)oc*32;
    #pragma unroll 8
    for (int k = 0; k < 32; k++) facc += __shfl(out, k, 32) * wr[k];
    float sp = fmaxf(facc, 0.f) + log1pf(expf(-fabsf(facc)));  // precise (final output)
    y[(size_t)g*64 + oc] = facc * tanhf(sp);
  }
}

extern "C" void kernel_launch(void* const* d_in, const int* in_sizes, int n_in,
                              void* d_out, int out_size, void* d_ws, size_t ws_size,
                              hipStream_t stream){
  const float* x_in     = (const float*)d_in[0];
  const float* ea       = (const float*)d_in[1];
  const int*   ei       = (const int*)  d_in[2];
  const int*   batch    = (const int*)  d_in[3];
  const float* lin1_w   = (const float*)d_in[4];
  const float* lin1_b   = (const float*)d_in[5];
  const float* g_lin1_w = (const float*)d_in[6];
  const float* g_lin2_w = (const float*)d_in[7];
  const float* g_att_l  = (const float*)d_in[8];
  const float* g_att_r  = (const float*)d_in[9];
  const float* g_bias   = (const float*)d_in[10];
  const float* gru1_wih = (const float*)d_in[11];
  const float* gru1_whh = (const float*)d_in[12];
  const float* gru1_bih = (const float*)d_in[13];
  const float* gru1_bhh = (const float*)d_in[14];
  const float* a_lin_w  = (const float*)d_in[15];
  const float* a_att_src= (const float*)d_in[16];
  const float* a_att_dst= (const float*)d_in[17];
  const float* a_bias   = (const float*)d_in[18];
  const float* gru2_wih = (const float*)d_in[19];
  const float* gru2_whh = (const float*)d_in[20];
  const float* gru2_bih = (const float*)d_in[21];
  const float* gru2_bhh = (const float*)d_in[22];
  const float* m_lin_w  = (const float*)d_in[23];
  const float* m_att_src= (const float*)d_in[24];
  const float* m_att_dst= (const float*)d_in[25];
  const float* m_bias   = (const float*)d_in[26];
  const float* gru3_wih = (const float*)d_in[27];
  const float* gru3_whh = (const float*)d_in[28];
  const float* gru3_bih = (const float*)d_in[29];
  const float* gru3_bhh = (const float*)d_in[30];
  const float* lin2_w   = (const float*)d_in[31];
  const float* lin2_b   = (const float*)d_in[32];

  float* W = (float*)d_ws;
  float* X     = W;                      // NN*32 f32
  bf16*  UV    = (bf16*)(W + 8388608);   // NN*64 bf16 interleaved u|v (32MB);
                                         // first 16MB reused as xt/xs after conv1
  bf16*  XT    = (bf16*)(W + 8388608);   // NN*32 bf16 : xt (gru1 out) / xs (gru2 out)
  int2*  EPK   = (int2*) (W + 16777216); // NE x (src, ea-bits)
  int*   RP1   = (int*)  (W + 20971520); // NN partial scan (dead after k_mid)
  bf16*  BC    = (bf16*) (W + 20971520); // NN*32 bf16 : h1 / h2 (after mid)
  int*   RANK  = (int*)  (W + 23068672); // NE within-dst ranks
  int*   ROWPTR= (int*)  (W + 25165824); // NN+1 (pad)
  int*   HIST  = (int*)  (W + 25428032); // NN
  int*   BTOT  = (int*)  (W + 25690176); // 1024
  float* NS1   = W + 25691200;           // NN : nr / al / a_node
  float* NS2   = W + 25953344;           // NN : ar
  int*   GPTR  = (int*)  (W + 26215488); // NG+1 (pad)

  dim3 b(THREADS);
  const int gNode  = NN/THREADS;        // 1024
  const int gNode32= NN/(THREADS/32);   // 32768
  const int gMFMA  = NN/(16*8*4);       // 512
  const int gRO    = NG/(THREADS/32);   // 1024

  // zero HIST (must precede k_front's histrank section)
  k_filli<<<gNode, b, 0, stream>>>(HIST, 0, NN);

  // FRONT: embed (MFMA, interleaved UV) ∥ histrank (atomics) ∥ gptr
  k_front<<<FB_EMBED + FB_HIST + FB_GPTR, b, 0, stream>>>(
      x_in, lin1_w, lin1_b, g_lin1_w, g_lin2_w, g_att_r, X, UV, NS1,
      ei, HIST, RANK, batch, GPTR);

  // scans; MID: final rowptr ∥ atomic-free place
  k_scan1<<<gNode, b, 0, stream>>>(HIST, RP1, BTOT);
  k_scan2<<<1, 1024, 0, stream>>>(BTOT);
  k_mid<<<MB_SCAN + NE/THREADS, b, 0, stream>>>(RP1, BTOT, ROWPTR, ei, ea, RANK, EPK);

  // GATEConv (inline score from UV u-half; gather v-half, stride 64, voff 32) + GRU1
  k_conv<<<gNode32, b, 0, stream>>>(ROWPTR, EPK, UV, g_lin1_w, g_att_l,
      nullptr, NS1, UV, 64, 32, g_bias, BC);
  k_gru_att<<<gMFMA, b, 0, stream>>>(BC, X, gru1_wih, gru1_whh, gru1_bih, gru1_bhh,
      a_lin_w, a_att_src, a_att_dst, XT, NS1, NS2);

  // GATConv (score = al[src]+ar[dst]; gather xt, stride 32) + GRU2
  k_conv<<<gNode32, b, 0, stream>>>(ROWPTR, EPK, nullptr, nullptr, nullptr,
      NS1, NS2, XT, 32, 0, a_bias, BC);
  k_gru_att<<<gMFMA, b, 0, stream>>>(BC, X, gru2_wih, gru2_whh, gru2_bih, gru2_bhh,
      m_lin_w, m_att_src, nullptr, XT, NS1, nullptr);

  // fused readout: rsum + q + 2x(softmax+GRU3) + final mish
  k_readout<<<gRO, b, 0, stream>>>(GPTR, X, NS1, XT, m_lin_w, m_att_dst, m_bias,
      gru3_wih, gru3_whh, gru3_bih, gru3_bhh, lin2_w, lin2_b, (float*)d_out);
}

// Round 20
// 403.923 us; speedup vs baseline: 1.4821x; 1.1166x over previous
//
#include <hip/hip_runtime.h>
#include <hip/hip_bf16.h>
#include <math.h>

#define NN 262144
#define NE 2097152
#define NG 8192
#define THREADS 256

typedef __hip_bfloat16 bf16;
typedef __attribute__((ext_vector_type(8))) short short8v;   // 8 bf16 (4 VGPRs)
typedef __attribute__((ext_vector_type(4))) float f32x4;

static __device__ __forceinline__ float lrelu(float x){ return x > 0.f ? x : 0.01f*x; }
static __device__ __forceinline__ float eluf(float x){ return x > 0.f ? x : __expf(x) - 1.f; }
static __device__ __forceinline__ float sigm(float x){ return 1.f/(1.f + __expf(-x)); }
static __device__ __forceinline__ float tanh_fast(float x){
  float e = __expf(2.f*x); return 1.f - 2.f/(e + 1.f);
}
static __device__ __forceinline__ float b2f(bf16 v){ return __bfloat162float(v); }
static __device__ __forceinline__ bf16 f2b(float v){ return __float2bfloat16(v); }
// bit-reinterpret a raw bf16 (held in a short) to float — NEVER value-convert!
static __device__ __forceinline__ float s2f(short s){
  return __uint_as_float(((unsigned int)(unsigned short)s) << 16);
}

static __device__ __forceinline__ unsigned short bfbits(float f){
  union { bf16 b; unsigned short s; } u; u.b = f2b(f); return u.s;
}
static __device__ __forceinline__ unsigned int pack2(float lo, float hi){
  return (unsigned int)bfbits(lo) | ((unsigned int)bfbits(hi) << 16);
}

static __device__ __forceinline__ float redsum32(float t){
  #pragma unroll
  for (int o = 16; o > 0; o >>= 1) t += __shfl_xor(t, o, 32);
  return t;
}

// GRU helper for the readout kernel (32 lanes = one row)
static __device__ __forceinline__ float gru_relu(float hv, float xv, int c,
    const float* __restrict__ wih, const float* __restrict__ whh,
    const float* __restrict__ bih, const float* __restrict__ bhh){
  float gr = bih[c], gz = bih[32+c], gn = bih[64+c];
  float hr = bhh[c], hz = bhh[32+c], hn = bhh[64+c];
  #pragma unroll 8
  for (int k = 0; k < 32; k++){
    float hk = __shfl(hv, k, 32);
    float xk = __shfl(xv, k, 32);
    gr += hk*wih[(     c)*32 + k];
    gz += hk*wih[(32 + c)*32 + k];
    gn += hk*wih[(64 + c)*32 + k];
    hr += xk*whh[(     c)*32 + k];
    hz += xk*whh[(32 + c)*32 + k];
    hn += xk*whh[(64 + c)*32 + k];
  }
  float r = sigm(gr + hr), z = sigm(gz + hz);
  float nn2 = tanh_fast(gn + r*hn);
  return fmaxf((1.f - z)*nn2 + z*xv, 0.f);
}

__global__ __launch_bounds__(THREADS) void k_filli(int* __restrict__ p, int v, int n){
  int i = blockIdx.x*THREADS + threadIdx.x;
  if (i < n) p[i] = v;
}

// ================= FRONT mega-kernel: embed (MFMA) ∥ histrank ∥ gptr ==========
// embed writes u/v INTERLEAVED: uv[node*64 + 0..31] = u row, +32..63 = v row.
#define FB_EMBED 512
#define FB_HIST  8192
#define FB_GPTR  1024

__global__ __launch_bounds__(THREADS) void k_front(
    const float* __restrict__ xin, const float* __restrict__ lw, const float* __restrict__ lb,
    const float* __restrict__ w1, const float* __restrict__ w2,
    const float* __restrict__ attr_r, float* __restrict__ X,
    bf16* __restrict__ uv, float* __restrict__ nr,
    const int* __restrict__ ei, int* __restrict__ hist, int* __restrict__ rank,
    const int* __restrict__ batch, int* __restrict__ gptr){
  __shared__ float ol[4][16][33];
  int bid = blockIdx.x;
  if (bid < FB_EMBED){
    int wid  = bid*4 + (threadIdx.x >> 6);
    int wv   = threadIdx.x >> 6;
    int lane = threadIdx.x & 63;
    int cl = lane & 15;
    int kb = lane >> 4;
    short8v BL[2][2], BU[2], BV[2];
    #pragma unroll
    for (int g = 0; g < 2; g++){
      #pragma unroll
      for (int kc = 0; kc < 2; kc++){
        short8v t;
        #pragma unroll
        for (int j = 0; j < 8; j++){
          int k = kc*32 + kb*8 + j;
          t[j] = (k < 54) ? (short)bfbits(lw[(size_t)(g*16+cl)*54 + k]) : (short)0;
        }
        BL[g][kc] = t;
      }
      short8v tu, tv;
      #pragma unroll
      for (int j = 0; j < 8; j++){
        tu[j] = (short)bfbits(w1[(size_t)(g*16+cl)*33 + kb*8 + j]);
        tv[j] = (short)bfbits(w2[(size_t)(g*16+cl)*32 + kb*8 + j]);
      }
      BU[g] = tu; BV[g] = tv;
    }
    float bb0 = lb[cl], bb1 = lb[16+cl];
    float ar0 = attr_r[cl], ar1 = attr_r[16+cl];
    f32x4 zero; zero[0]=0.f; zero[1]=0.f; zero[2]=0.f; zero[3]=0.f;

    for (int t = 0; t < 8; t++){
      int nb = (wid*8 + t)*16;
      const float* xrow = xin + (size_t)(nb + cl)*54;
      short8v Ax0, Ax1;
      const float2* x2 = (const float2*)(xrow + kb*8);
      #pragma unroll
      for (int jj = 0; jj < 4; jj++){
        float2 tvv = x2[jj];
        Ax0[2*jj]   = (short)bfbits(tvv.x);
        Ax0[2*jj+1] = (short)bfbits(tvv.y);
      }
      #pragma unroll
      for (int j = 0; j < 8; j++){
        int k = 32 + kb*8 + j;
        Ax1[j] = (k < 54) ? (short)bfbits(xrow[k]) : (short)0;
      }
      f32x4 a0, a1;
      #pragma unroll
      for (int q = 0; q < 4; q++){ a0[q] = bb0; a1[q] = bb1; }
      f32x4 d0 = __builtin_amdgcn_mfma_f32_16x16x32_bf16(Ax0, BL[0][0], a0, 0, 0, 0);
      d0 = __builtin_amdgcn_mfma_f32_16x16x32_bf16(Ax1, BL[0][1], d0, 0, 0, 0);
      f32x4 d1 = __builtin_amdgcn_mfma_f32_16x16x32_bf16(Ax0, BL[1][0], a1, 0, 0, 0);
      d1 = __builtin_amdgcn_mfma_f32_16x16x32_bf16(Ax1, BL[1][1], d1, 0, 0, 0);
      #pragma unroll
      for (int r = 0; r < 4; r++){ d0[r] = lrelu(d0[r]); d1[r] = lrelu(d1[r]); }
      #pragma unroll
      for (int r = 0; r < 4; r++){
        int node = nb + kb*4 + r;
        float* srow = X + (size_t)node*32;
        srow[cl]      = d0[r];
        srow[16 + cl] = d1[r];
        ol[wv][kb*4 + r][cl]      = d0[r];
        ol[wv][kb*4 + r][16 + cl] = d1[r];
      }
      #pragma unroll
      for (int r = 0; r < 4; r++){
        float vsum = d0[r]*ar0 + d1[r]*ar1;
        vsum += __shfl_xor(vsum, 1, 16);
        vsum += __shfl_xor(vsum, 2, 16);
        vsum += __shfl_xor(vsum, 4, 16);
        vsum += __shfl_xor(vsum, 8, 16);
        if (cl == 0) nr[nb + kb*4 + r] = vsum;
      }
      __syncthreads();
      short8v Ao;
      #pragma unroll
      for (int j = 0; j < 8; j++) Ao[j] = (short)bfbits(ol[wv][cl][kb*8 + j]);
      f32x4 u0 = __builtin_amdgcn_mfma_f32_16x16x32_bf16(Ao, BU[0], zero, 0, 0, 0);
      f32x4 u1 = __builtin_amdgcn_mfma_f32_16x16x32_bf16(Ao, BU[1], zero, 0, 0, 0);
      f32x4 v0 = __builtin_amdgcn_mfma_f32_16x16x32_bf16(Ao, BV[0], zero, 0, 0, 0);
      f32x4 v1 = __builtin_amdgcn_mfma_f32_16x16x32_bf16(Ao, BV[1], zero, 0, 0, 0);
      #pragma unroll
      for (int r = 0; r < 4; r++){
        int node = nb + kb*4 + r;
        bf16* rowp = uv + (size_t)node*64;     // interleaved u|v row (128B)
        rowp[cl]           = f2b(u0[r]);
        rowp[16 + cl]      = f2b(u1[r]);
        rowp[32 + cl]      = f2b(v0[r]);
        rowp[48 + cl]      = f2b(v1[r]);
      }
      __syncthreads();
    }
  } else if (bid < FB_EMBED + FB_HIST){
    int e = (bid - FB_EMBED)*THREADS + threadIdx.x;
    rank[e] = atomicAdd(hist + ei[NE + e], 1);
  } else {
    int n = (bid - FB_EMBED - FB_HIST)*THREADS + threadIdx.x;
    int bc = batch[n];
    if (n == 0){ for (int g = 0; g <= bc; g++) gptr[g] = 0; }
    else {
      int pb = batch[n-1];
      if (pb != bc) for (int g = pb+1; g <= bc; g++) gptr[g] = n;
    }
    if (n == NN-1){ for (int g = bc+1; g <= NG; g++) gptr[g] = NN; }
  }
}

// ---------------- scans ----------------
__global__ __launch_bounds__(THREADS) void k_scan1(const int* __restrict__ hist,
    int* __restrict__ rp1, int* __restrict__ btot){
  __shared__ int sh[THREADS];
  int i = blockIdx.x*THREADS + threadIdx.x;
  int v = hist[i];
  sh[threadIdx.x] = v; __syncthreads();
  #pragma unroll
  for (int off = 1; off < THREADS; off <<= 1){
    int t = (threadIdx.x >= off) ? sh[threadIdx.x - off] : 0;
    __syncthreads(); sh[threadIdx.x] += t; __syncthreads();
  }
  rp1[i] = sh[threadIdx.x] - v;
  if (threadIdx.x == THREADS-1) btot[blockIdx.x] = sh[THREADS-1];
}

__global__ __launch_bounds__(1024) void k_scan2(int* __restrict__ btot){
  __shared__ int sh[1024];
  int i = threadIdx.x;
  int v = btot[i];
  sh[i] = v; __syncthreads();
  for (int off = 1; off < 1024; off <<= 1){
    int t = (i >= off) ? sh[i - off] : 0;
    __syncthreads(); sh[i] += t; __syncthreads();
  }
  btot[i] = sh[i] - v;  // exclusive
}

// ======== MID mega-kernel: final rowptr ∥ atomic-free place ==================
#define MB_SCAN 1024

__global__ __launch_bounds__(THREADS) void k_mid(const int* __restrict__ rp1,
    const int* __restrict__ btot, int* __restrict__ rowptr,
    const int* __restrict__ ei, const float* __restrict__ ea,
    const int* __restrict__ rank, int2* __restrict__ epk){
  int bid = blockIdx.x;
  if (bid < MB_SCAN){
    int i = bid*THREADS + threadIdx.x;
    rowptr[i] = rp1[i] + btot[i >> 8];
    if (i == 0) rowptr[NN] = NE;
  } else {
    int e = (bid - MB_SCAN)*THREADS + threadIdx.x;
    int d = ei[NE + e];
    int pos = rp1[d] + btot[d >> 8] + rank[e];
    epk[pos] = make_int2(ei[e], __float_as_int(ea[e]));
  }
}

// ---- GRU via MFMA + fused att precompute (proven form) ----
__global__ __launch_bounds__(THREADS) void k_gru_att(const bf16* __restrict__ HV,
    float* __restrict__ S,
    const float* __restrict__ wih, const float* __restrict__ whh,
    const float* __restrict__ bih, const float* __restrict__ bhh,
    const float* __restrict__ attW, const float* __restrict__ att1,
    const float* __restrict__ att2,
    bf16* __restrict__ xt, float* __restrict__ s1, float* __restrict__ s2){
  __shared__ float ol[4][16][33];
  int wid  = (blockIdx.x*THREADS + threadIdx.x) >> 6;
  int wv   = threadIdx.x >> 6;
  int lane = threadIdx.x & 63;
  int cl = lane & 15;
  int kb = lane >> 4;
  short8v BW[12], BT[2];
  #pragma unroll
  for (int g = 0; g < 6; g++){
    const float* wr = wih + (size_t)(g*16 + cl)*32 + kb*8;
    const float* vr = whh + (size_t)(g*16 + cl)*32 + kb*8;
    short8v bw, bv;
    #pragma unroll
    for (int j = 0; j < 8; j++){ bw[j] = (short)bfbits(wr[j]); bv[j] = (short)bfbits(vr[j]); }
    BW[g] = bw; BW[6+g] = bv;
  }
  #pragma unroll
  for (int g = 0; g < 2; g++){
    short8v bt;
    #pragma unroll
    for (int j = 0; j < 8; j++) bt[j] = (short)bfbits(attW[(size_t)(g*16+cl)*32 + kb*8 + j]);
    BT[g] = bt;
  }
  float bI[6], bH[6];
  #pragma unroll
  for (int g = 0; g < 6; g++){ bI[g] = bih[g*16 + cl]; bH[g] = bhh[g*16 + cl]; }
  float a1c0 = att1[cl], a1c1 = att1[16+cl];
  float a2c0 = att2 ? att2[cl] : 0.f, a2c1 = att2 ? att2[16+cl] : 0.f;
  f32x4 zero; zero[0]=0.f; zero[1]=0.f; zero[2]=0.f; zero[3]=0.f;

  for (int t = 0; t < 8; t++){
    int nb = (wid*8 + t) * 16;
    short8v Ah = *(const short8v*)(HV + (size_t)(nb + cl)*32 + kb*8);
    const float* xr = S + (size_t)(nb + cl)*32 + kb*8;
    short8v Ax;
    #pragma unroll
    for (int j = 0; j < 8; j++) Ax[j] = (short)bfbits(xr[j]);
    f32x4 gi[6], gh[6];
    #pragma unroll
    for (int g = 0; g < 6; g++){
      f32x4 a, b;
      #pragma unroll
      for (int q = 0; q < 4; q++){ a[q] = bI[g]; b[q] = bH[g]; }
      gi[g] = __builtin_amdgcn_mfma_f32_16x16x32_bf16(Ah, BW[g],   a, 0, 0, 0);
      gh[g] = __builtin_amdgcn_mfma_f32_16x16x32_bf16(Ax, BW[6+g], b, 0, 0, 0);
    }
    #pragma unroll
    for (int r = 0; r < 4; r++){
      int node = nb + kb*4 + r;
      float* srow = S + (size_t)node*32;
      float x0 = srow[cl], x1 = srow[16 + cl];
      float r0 = sigm(gi[0][r] + gh[0][r]);
      float z0 = sigm(gi[2][r] + gh[2][r]);
      float n0 = tanh_fast(gi[4][r] + r0*gh[4][r]);
      float r1 = sigm(gi[1][r] + gh[1][r]);
      float z1 = sigm(gi[3][r] + gh[3][r]);
      float n1 = tanh_fast(gi[5][r] + r1*gh[5][r]);
      float o0 = fmaxf((1.f - z0)*n0 + z0*x0, 0.f);
      float o1 = fmaxf((1.f - z1)*n1 + z1*x1, 0.f);
      srow[cl]      = o0;
      srow[16 + cl] = o1;
      ol[wv][kb*4 + r][cl]      = o0;
      ol[wv][kb*4 + r][16 + cl] = o1;
    }
    __syncthreads();
    short8v Ao;
    #pragma unroll
    for (int j = 0; j < 8; j++) Ao[j] = (short)bfbits(ol[wv][cl][kb*8 + j]);
    f32x4 t0 = __builtin_amdgcn_mfma_f32_16x16x32_bf16(Ao, BT[0], zero, 0, 0, 0);
    f32x4 t1 = __builtin_amdgcn_mfma_f32_16x16x32_bf16(Ao, BT[1], zero, 0, 0, 0);
    #pragma unroll
    for (int r = 0; r < 4; r++){
      int node = nb + kb*4 + r;
      bf16* xrow = xt + (size_t)node*32;
      xrow[cl]      = f2b(t0[r]);
      xrow[16 + cl] = f2b(t1[r]);
      float p1 = t0[r]*a1c0 + t1[r]*a1c1;
      p1 += __shfl_xor(p1, 1, 16);
      p1 += __shfl_xor(p1, 2, 16);
      p1 += __shfl_xor(p1, 4, 16);
      p1 += __shfl_xor(p1, 8, 16);
      if (cl == 0) s1[node] = p1;
      if (att2){
        float p2 = t0[r]*a2c0 + t1[r]*a2c1;
        p2 += __shfl_xor(p2, 1, 16);
        p2 += __shfl_xor(p2, 2, 16);
        p2 += __shfl_xor(p2, 4, 16);
        p2 += __shfl_xor(p2, 8, 16);
        if (cl == 0) s2[node] = p2;
      }
    }
    __syncthreads();
  }
}

// ---- conv v5: 4 nodes per 32-lane group (8 lanes/node) — full-util score pass.
// Gather rows at ROWS + si*rstride + voff (conv1: UV interleaved; conv2: linear xt).
__global__ __launch_bounds__(THREADS) void k_conv(const int* __restrict__ rowptr,
    const int2* __restrict__ epk, const bf16* __restrict__ U,
    const float* __restrict__ w1 /*32x33*/, const float* __restrict__ attl,
    const float* __restrict__ alsrc, const float* __restrict__ term,
    const bf16* __restrict__ ROWS, int rstride, int voff,
    const float* __restrict__ bias, bf16* __restrict__ HV){
  int grp = blockIdx.x*(THREADS/32) + (threadIdx.x >> 5);
  int c32 = threadIdx.x & 31;
  int sub = c32 >> 3;          // node within group (0..3)
  int l8  = c32 & 7;           // lane within node
  int node = grp*4 + sub;
  int ws = rowptr[node], we = rowptr[node+1];
  float tv = term[node];
  float wc[32], at[32];        // wave-uniform -> SGPRs
  if (U){
    #pragma unroll
    for (int j = 0; j < 32; j++){ wc[j] = w1[j*33 + 32]; at[j] = attl[j]; }
  }
  int eh = l8 >> 2, cb = l8 & 3;
  float sl = 0.f;
  float acc[8];
  #pragma unroll
  for (int j = 0; j < 8; j++) acc[j] = 0.f;
  for (int p0 = ws; p0 < we; p0 += 8){
    int p = p0 + l8;
    bool ok = p < we;
    int pc = ok ? p : ws;
    int2 pk = epk[pc];
    int siA = pk.x;
    float sc;
    if (U){
      float a = __int_as_float(pk.y);
      const short8v* ur = (const short8v*)(U + (size_t)siA*64);  // u-half of UV row
      sc = 0.f;
      #pragma unroll
      for (int q = 0; q < 4; q++){
        short8v u8 = ur[q];
        #pragma unroll
        for (int j = 0; j < 8; j++)
          sc += at[q*8+j]*lrelu(s2f(u8[j]) + a*wc[q*8+j]);
      }
    } else {
      sc = alsrc[siA];
    }
    float wme = ok ? __expf(lrelu(sc + tv)) : 0.f;
    sl += wme;
    #pragma unroll
    for (int se = 0; se < 4; se++){
      if (p0 + se*2 >= we) break;
      int lsrc = sub*8 + se*2 + eh;
      float w = __shfl(wme, lsrc, 32);
      int si  = __shfl(siA, lsrc, 32);
      short8v r8 = *(const short8v*)(ROWS + (size_t)si*rstride + voff + cb*8);
      #pragma unroll
      for (int j = 0; j < 8; j++) acc[j] += s2f(r8[j]) * w;
    }
  }
  // denominator: sum over the 8 lanes of this sub-group
  sl += __shfl_xor(sl, 1, 32);
  sl += __shfl_xor(sl, 2, 32);
  sl += __shfl_xor(sl, 4, 32);
  float inv = 1.f/(sl + 1e-16f);
  // combine the eh pair
  #pragma unroll
  for (int j = 0; j < 8; j++) acc[j] += __shfl_xor(acc[j], 4, 32);
  if (eh == 0){
    unsigned int o[4];
    #pragma unroll
    for (int j2 = 0; j2 < 4; j2++){
      float h0 = eluf(acc[2*j2  ]*inv + bias[cb*8 + 2*j2  ]);
      float h1 = eluf(acc[2*j2+1]*inv + bias[cb*8 + 2*j2+1]);
      o[j2] = pack2(h0, h1);
    }
    *(uint4*)(HV + (size_t)node*32 + cb*8) = make_uint4(o[0], o[1], o[2], o[3]);
  }
}

// ======== fused readout: rsum + q + 2x(softmax+GRU3) + final mish ===========
__global__ __launch_bounds__(THREADS) void k_readout(const int* __restrict__ gptr,
    const float* __restrict__ X, const float* __restrict__ anode,
    const bf16* __restrict__ XS,
    const float* __restrict__ mw /*m_lin_w*/, const float* __restrict__ mattd,
    const float* __restrict__ mbias,
    const float* __restrict__ wih, const float* __restrict__ whh,
    const float* __restrict__ bih, const float* __restrict__ bhh,
    const float* __restrict__ lin2_w, const float* __restrict__ lin2_b,
    float* __restrict__ y){
  int g = blockIdx.x*(THREADS/32) + (threadIdx.x >> 5);
  int c = threadIdx.x & 31;
  int gs = gptr[g], ge = gptr[g+1];
  // rsum + relu
  float out = 0.f;
  for (int n = gs; n < ge; n++) out += X[(size_t)n*32 + c];
  out = fmaxf(out, 0.f);
  // q[c]
  float qc = 0.f;
  #pragma unroll
  for (int j = 0; j < 32; j++) qc += mattd[j]*mw[j*32 + c];
  // 2 timesteps
  #pragma unroll 1
  for (int t = 0; t < 2; t++){
    float ag = redsum32(out * qc);
    float s = 0.f;
    for (int p0 = gs; p0 < ge; p0 += 32){
      int p = p0 + c;
      float e = (p < ge) ? __expf(lrelu(anode[p] + ag)) : 0.f;
      s += redsum32(e);
    }
    float inv = 1.f/(s + 1e-16f);
    float acc = 0.f;
    int n = gs;
    for (; n + 4 <= ge; n += 4){
      float e0 = __expf(lrelu(anode[n]   + ag));
      float e1 = __expf(lrelu(anode[n+1] + ag));
      float e2 = __expf(lrelu(anode[n+2] + ag));
      float e3 = __expf(lrelu(anode[n+3] + ag));
      acc += b2f(XS[(size_t)(n  )*32 + c])*e0 + b2f(XS[(size_t)(n+1)*32 + c])*e1
           + b2f(XS[(size_t)(n+2)*32 + c])*e2 + b2f(XS[(size_t)(n+3)*32 + c])*e3;
    }
    for (; n < ge; n++)
      acc += b2f(XS[(size_t)n*32 + c]) * __expf(lrelu(anode[n] + ag));
    acc *= inv;
    float hv = eluf(acc + mbias[c]);
    out = gru_relu(hv, out, c, wih, whh, bih, bhh);
  }
  // final: y = mish(out @ lin2^T + b)
  #pragma unroll
  for (int oc2 = 0; oc2 < 2; oc2++){
    int oc = oc2*32 + c;
    float facc = lin2_b[oc];
    const float* wr = lin2_w + (size_t)oc*32;
    #pragma unroll 8
    for (int k = 0; k < 32; k++) facc += __shfl(out, k, 32) * wr[k];
    float sp = fmaxf(facc, 0.f) + log1pf(expf(-fabsf(facc)));  // precise (final output)
    y[(size_t)g*64 + oc] = facc * tanhf(sp);
  }
}

extern "C" void kernel_launch(void* const* d_in, const int* in_sizes, int n_in,
                              void* d_out, int out_size, void* d_ws, size_t ws_size,
                              hipStream_t stream){
  const float* x_in     = (const float*)d_in[0];
  const float* ea       = (const float*)d_in[1];
  const int*   ei       = (const int*)  d_in[2];
  const int*   batch    = (const int*)  d_in[3];
  const float* lin1_w   = (const float*)d_in[4];
  const float* lin1_b   = (const float*)d_in[5];
  const float* g_lin1_w = (const float*)d_in[6];
  const float* g_lin2_w = (const float*)d_in[7];
  const float* g_att_l  = (const float*)d_in[8];
  const float* g_att_r  = (const float*)d_in[9];
  const float* g_bias   = (const float*)d_in[10];
  const float* gru1_wih = (const float*)d_in[11];
  const float* gru1_whh = (const float*)d_in[12];
  const float* gru1_bih = (const float*)d_in[13];
  const float* gru1_bhh = (const float*)d_in[14];
  const float* a_lin_w  = (const float*)d_in[15];
  const float* a_att_src= (const float*)d_in[16];
  const float* a_att_dst= (const float*)d_in[17];
  const float* a_bias   = (const float*)d_in[18];
  const float* gru2_wih = (const float*)d_in[19];
  const float* gru2_whh = (const float*)d_in[20];
  const float* gru2_bih = (const float*)d_in[21];
  const float* gru2_bhh = (const float*)d_in[22];
  const float* m_lin_w  = (const float*)d_in[23];
  const float* m_att_src= (const float*)d_in[24];
  const float* m_att_dst= (const float*)d_in[25];
  const float* m_bias   = (const float*)d_in[26];
  const float* gru3_wih = (const float*)d_in[27];
  const float* gru3_whh = (const float*)d_in[28];
  const float* gru3_bih = (const float*)d_in[29];
  const float* gru3_bhh = (const float*)d_in[30];
  const float* lin2_w   = (const float*)d_in[31];
  const float* lin2_b   = (const float*)d_in[32];

  float* W = (float*)d_ws;
  float* X     = W;                      // NN*32 f32
  bf16*  UV    = (bf16*)(W + 8388608);   // NN*64 bf16 interleaved u|v (32MB)
  bf16*  XT    = (bf16*)(W + 8388608);   // NN*32 bf16 : xt/xs (reuses UV after conv1)
  int2*  EPK   = (int2*) (W + 16777216); // NE x (src, ea-bits)
  int*   RP1   = (int*)  (W + 20971520); // NN partial scan (dead after k_mid)
  bf16*  BC    = (bf16*) (W + 20971520); // NN*32 bf16 : h1 / h2 (after mid)
  int*   RANK  = (int*)  (W + 23068672); // NE within-dst ranks
  int*   ROWPTR= (int*)  (W + 25165824); // NN+1 (pad)
  int*   HIST  = (int*)  (W + 25428032); // NN
  int*   BTOT  = (int*)  (W + 25690176); // 1024
  float* NS1   = W + 25691200;           // NN : nr / al / a_node
  float* NS2   = W + 25953344;           // NN : ar
  int*   GPTR  = (int*)  (W + 26215488); // NG+1 (pad)

  dim3 b(THREADS);
  const int gNode  = NN/THREADS;        // 1024
  const int gConv  = NN/32;             // 8192 : conv v5 (32 nodes/block)
  const int gMFMA  = NN/(16*8*4);       // 512
  const int gRO    = NG/(THREADS/32);   // 1024

  // zero HIST (must precede k_front's histrank section)
  k_filli<<<gNode, b, 0, stream>>>(HIST, 0, NN);

  // FRONT: embed (MFMA, interleaved UV) ∥ histrank (atomics) ∥ gptr
  k_front<<<FB_EMBED + FB_HIST + FB_GPTR, b, 0, stream>>>(
      x_in, lin1_w, lin1_b, g_lin1_w, g_lin2_w, g_att_r, X, UV, NS1,
      ei, HIST, RANK, batch, GPTR);

  // scans; MID: final rowptr ∥ atomic-free place
  k_scan1<<<gNode, b, 0, stream>>>(HIST, RP1, BTOT);
  k_scan2<<<1, 1024, 0, stream>>>(BTOT);
  k_mid<<<MB_SCAN + NE/THREADS, b, 0, stream>>>(RP1, BTOT, ROWPTR, ei, ea, RANK, EPK);

  // GATEConv (inline score from UV u-half; gather v-half, stride 64, voff 32) + GRU1
  k_conv<<<gConv, b, 0, stream>>>(ROWPTR, EPK, UV, g_lin1_w, g_att_l,
      nullptr, NS1, UV, 64, 32, g_bias, BC);
  k_gru_att<<<gMFMA, b, 0, stream>>>(BC, X, gru1_wih, gru1_whh, gru1_bih, gru1_bhh,
      a_lin_w, a_att_src, a_att_dst, XT, NS1, NS2);

  // GATConv (score = al[src]+ar[dst]; gather xt, stride 32) + GRU2
  k_conv<<<gConv, b, 0, stream>>>(ROWPTR, EPK, nullptr, nullptr, nullptr,
      NS1, NS2, XT, 32, 0, a_bias, BC);
  k_gru_att<<<gMFMA, b, 0, stream>>>(BC, X, gru2_wih, gru2_whh, gru2_bih, gru2_bhh,
      m_lin_w, m_att_src, nullptr, XT, NS1, nullptr);

  // fused readout: rsum + q + 2x(softmax+GRU3) + final mish
  k_readout<<<gRO, b, 0, stream>>>(GPTR, X, NS1, XT, m_lin_w, m_att_dst, m_bias,
      gru3_wih, gru3_whh, gru3_bih, gru3_bhh, lin2_w, lin2_b, (float*)d_out);
}

// Round 21
// 391.404 us; speedup vs baseline: 1.5295x; 1.0320x over previous
//
#include <hip/hip_runtime.h>
#include <hip/hip_bf16.h>
#include <math.h>

#define NN 262144
#define NE 2097152
#define NG 8192
#define THREADS 256

typedef __hip_bfloat16 bf16;
typedef __attribute__((ext_vector_type(8))) short short8v;   // 8 bf16 (4 VGPRs)
typedef __attribute__((ext_vector_type(4))) float f32x4;

static __device__ __forceinline__ float lrelu(float x){ return x > 0.f ? x : 0.01f*x; }
static __device__ __forceinline__ float eluf(float x){ return x > 0.f ? x : __expf(x) - 1.f; }
static __device__ __forceinline__ float sigm(float x){ return 1.f/(1.f + __expf(-x)); }
static __device__ __forceinline__ float tanh_fast(float x){
  float e = __expf(2.f*x); return 1.f - 2.f/(e + 1.f);
}
static __device__ __forceinline__ float b2f(bf16 v){ return __bfloat162float(v); }
static __device__ __forceinline__ bf16 f2b(float v){ return __float2bfloat16(v); }
// bit-reinterpret a raw bf16 (held in a short) to float — NEVER value-convert!
static __device__ __forceinline__ float s2f(short s){
  return __uint_as_float(((unsigned int)(unsigned short)s) << 16);
}

static __device__ __forceinline__ unsigned short bfbits(float f){
  union { bf16 b; unsigned short s; } u; u.b = f2b(f); return u.s;
}
static __device__ __forceinline__ unsigned int pack2(float lo, float hi){
  return (unsigned int)bfbits(lo) | ((unsigned int)bfbits(hi) << 16);
}

static __device__ __forceinline__ float redsum32(float t){
  #pragma unroll
  for (int o = 16; o > 0; o >>= 1) t += __shfl_xor(t, o, 32);
  return t;
}

// GRU helper for the readout kernel (32 lanes = one row)
static __device__ __forceinline__ float gru_relu(float hv, float xv, int c,
    const float* __restrict__ wih, const float* __restrict__ whh,
    const float* __restrict__ bih, const float* __restrict__ bhh){
  float gr = bih[c], gz = bih[32+c], gn = bih[64+c];
  float hr = bhh[c], hz = bhh[32+c], hn = bhh[64+c];
  #pragma unroll 8
  for (int k = 0; k < 32; k++){
    float hk = __shfl(hv, k, 32);
    float xk = __shfl(xv, k, 32);
    gr += hk*wih[(     c)*32 + k];
    gz += hk*wih[(32 + c)*32 + k];
    gn += hk*wih[(64 + c)*32 + k];
    hr += xk*whh[(     c)*32 + k];
    hz += xk*whh[(32 + c)*32 + k];
    hn += xk*whh[(64 + c)*32 + k];
  }
  float r = sigm(gr + hr), z = sigm(gz + hz);
  float nn2 = tanh_fast(gn + r*hn);
  return fmaxf((1.f - z)*nn2 + z*xv, 0.f);
}

// ================= FRONT mega-kernel: embed (MFMA) ∥ histrank ∥ gptr ==========
// embed writes X in bf16 and u/v INTERLEAVED: uv[node*64+0..31]=u, +32..63=v.
#define FB_EMBED 512
#define FB_HIST  8192
#define FB_GPTR  1024

__global__ __launch_bounds__(THREADS) void k_front(
    const float* __restrict__ xin, const float* __restrict__ lw, const float* __restrict__ lb,
    const float* __restrict__ w1, const float* __restrict__ w2,
    const float* __restrict__ attr_r, bf16* __restrict__ X,
    bf16* __restrict__ uv, float* __restrict__ nr,
    const int* __restrict__ ei, int* __restrict__ hist, int* __restrict__ rank,
    const int* __restrict__ batch, int* __restrict__ gptr){
  __shared__ float ol[4][16][33];
  int bid = blockIdx.x;
  if (bid < FB_EMBED){
    int wid  = bid*4 + (threadIdx.x >> 6);
    int wv   = threadIdx.x >> 6;
    int lane = threadIdx.x & 63;
    int cl = lane & 15;
    int kb = lane >> 4;
    short8v BL[2][2], BU[2], BV[2];
    #pragma unroll
    for (int g = 0; g < 2; g++){
      #pragma unroll
      for (int kc = 0; kc < 2; kc++){
        short8v t;
        #pragma unroll
        for (int j = 0; j < 8; j++){
          int k = kc*32 + kb*8 + j;
          t[j] = (k < 54) ? (short)bfbits(lw[(size_t)(g*16+cl)*54 + k]) : (short)0;
        }
        BL[g][kc] = t;
      }
      short8v tu, tv;
      #pragma unroll
      for (int j = 0; j < 8; j++){
        tu[j] = (short)bfbits(w1[(size_t)(g*16+cl)*33 + kb*8 + j]);
        tv[j] = (short)bfbits(w2[(size_t)(g*16+cl)*32 + kb*8 + j]);
      }
      BU[g] = tu; BV[g] = tv;
    }
    float bb0 = lb[cl], bb1 = lb[16+cl];
    float ar0 = attr_r[cl], ar1 = attr_r[16+cl];
    f32x4 zero; zero[0]=0.f; zero[1]=0.f; zero[2]=0.f; zero[3]=0.f;

    for (int t = 0; t < 8; t++){
      int nb = (wid*8 + t)*16;
      const float* xrow = xin + (size_t)(nb + cl)*54;
      short8v Ax0, Ax1;
      const float2* x2 = (const float2*)(xrow + kb*8);
      #pragma unroll
      for (int jj = 0; jj < 4; jj++){
        float2 tvv = x2[jj];
        Ax0[2*jj]   = (short)bfbits(tvv.x);
        Ax0[2*jj+1] = (short)bfbits(tvv.y);
      }
      #pragma unroll
      for (int j = 0; j < 8; j++){
        int k = 32 + kb*8 + j;
        Ax1[j] = (k < 54) ? (short)bfbits(xrow[k]) : (short)0;
      }
      f32x4 a0, a1;
      #pragma unroll
      for (int q = 0; q < 4; q++){ a0[q] = bb0; a1[q] = bb1; }
      f32x4 d0 = __builtin_amdgcn_mfma_f32_16x16x32_bf16(Ax0, BL[0][0], a0, 0, 0, 0);
      d0 = __builtin_amdgcn_mfma_f32_16x16x32_bf16(Ax1, BL[0][1], d0, 0, 0, 0);
      f32x4 d1 = __builtin_amdgcn_mfma_f32_16x16x32_bf16(Ax0, BL[1][0], a1, 0, 0, 0);
      d1 = __builtin_amdgcn_mfma_f32_16x16x32_bf16(Ax1, BL[1][1], d1, 0, 0, 0);
      #pragma unroll
      for (int r = 0; r < 4; r++){ d0[r] = lrelu(d0[r]); d1[r] = lrelu(d1[r]); }
      #pragma unroll
      for (int r = 0; r < 4; r++){
        int node = nb + kb*4 + r;
        bf16* srow = X + (size_t)node*32;
        srow[cl]      = f2b(d0[r]);
        srow[16 + cl] = f2b(d1[r]);
        ol[wv][kb*4 + r][cl]      = d0[r];
        ol[wv][kb*4 + r][16 + cl] = d1[r];
      }
      #pragma unroll
      for (int r = 0; r < 4; r++){
        float vsum = d0[r]*ar0 + d1[r]*ar1;
        vsum += __shfl_xor(vsum, 1, 16);
        vsum += __shfl_xor(vsum, 2, 16);
        vsum += __shfl_xor(vsum, 4, 16);
        vsum += __shfl_xor(vsum, 8, 16);
        if (cl == 0) nr[nb + kb*4 + r] = vsum;
      }
      __syncthreads();
      short8v Ao;
      #pragma unroll
      for (int j = 0; j < 8; j++) Ao[j] = (short)bfbits(ol[wv][cl][kb*8 + j]);
      f32x4 u0 = __builtin_amdgcn_mfma_f32_16x16x32_bf16(Ao, BU[0], zero, 0, 0, 0);
      f32x4 u1 = __builtin_amdgcn_mfma_f32_16x16x32_bf16(Ao, BU[1], zero, 0, 0, 0);
      f32x4 v0 = __builtin_amdgcn_mfma_f32_16x16x32_bf16(Ao, BV[0], zero, 0, 0, 0);
      f32x4 v1 = __builtin_amdgcn_mfma_f32_16x16x32_bf16(Ao, BV[1], zero, 0, 0, 0);
      #pragma unroll
      for (int r = 0; r < 4; r++){
        int node = nb + kb*4 + r;
        bf16* rowp = uv + (size_t)node*64;     // interleaved u|v row (128B)
        rowp[cl]           = f2b(u0[r]);
        rowp[16 + cl]      = f2b(u1[r]);
        rowp[32 + cl]      = f2b(v0[r]);
        rowp[48 + cl]      = f2b(v1[r]);
      }
      __syncthreads();
    }
  } else if (bid < FB_EMBED + FB_HIST){
    int e = (bid - FB_EMBED)*THREADS + threadIdx.x;
    rank[e] = atomicAdd(hist + ei[NE + e], 1);
  } else {
    int n = (bid - FB_EMBED - FB_HIST)*THREADS + threadIdx.x;
    int bc = batch[n];
    if (n == 0){ for (int g = 0; g <= bc; g++) gptr[g] = 0; }
    else {
      int pb = batch[n-1];
      if (pb != bc) for (int g = pb+1; g <= bc; g++) gptr[g] = n;
    }
    if (n == NN-1){ for (int g = bc+1; g <= NG; g++) gptr[g] = NN; }
  }
}

// ---------------- scan1: per-chunk exclusive partials + raw chunk totals ----
__global__ __launch_bounds__(THREADS) void k_scan1(const int* __restrict__ hist,
    int* __restrict__ rp1, int* __restrict__ btot){
  __shared__ int sh[THREADS];
  int i = blockIdx.x*THREADS + threadIdx.x;
  int v = hist[i];
  sh[threadIdx.x] = v; __syncthreads();
  #pragma unroll
  for (int off = 1; off < THREADS; off <<= 1){
    int t = (threadIdx.x >= off) ? sh[threadIdx.x - off] : 0;
    __syncthreads(); sh[threadIdx.x] += t; __syncthreads();
  }
  rp1[i] = sh[threadIdx.x] - v;
  if (threadIdx.x == THREADS-1) btot[blockIdx.x] = sh[THREADS-1];
}

// ======== MID mega-kernel: local btot-scan + (final rowptr ∥ atomic-free place)
#define MB_SCAN 1024

__global__ __launch_bounds__(THREADS) void k_mid(const int* __restrict__ rp1,
    const int* __restrict__ btot, int* __restrict__ rowptr,
    const int* __restrict__ ei, const float* __restrict__ ea,
    const int* __restrict__ rank, int2* __restrict__ epk){
  __shared__ int bsum[THREADS];
  __shared__ int bpfx[1024];
  int t = threadIdx.x;
  // local exclusive scan of raw btot[0..1023]
  int v0 = btot[t*4+0], v1 = btot[t*4+1], v2 = btot[t*4+2], v3 = btot[t*4+3];
  int s4 = v0+v1+v2+v3;
  bsum[t] = s4; __syncthreads();
  #pragma unroll
  for (int off = 1; off < THREADS; off <<= 1){
    int tv = (t >= off) ? bsum[t-off] : 0;
    __syncthreads(); bsum[t] += tv; __syncthreads();
  }
  int run = bsum[t] - s4;
  bpfx[t*4+0] = run; run += v0;
  bpfx[t*4+1] = run; run += v1;
  bpfx[t*4+2] = run; run += v2;
  bpfx[t*4+3] = run;
  __syncthreads();
  int bid = blockIdx.x;
  if (bid < MB_SCAN){
    int i = bid*THREADS + t;
    rowptr[i] = rp1[i] + bpfx[i >> 8];
    if (i == 0) rowptr[NN] = NE;
  } else {
    int e = (bid - MB_SCAN)*THREADS + t;
    int d = ei[NE + e];
    int pos = rp1[d] + bpfx[d >> 8] + rank[e];
    epk[pos] = make_int2(ei[e], __float_as_int(ea[e]));
  }
}

// ---- GRU via MFMA + fused att precompute (bf16 X) ----
__global__ __launch_bounds__(THREADS) void k_gru_att(const bf16* __restrict__ HV,
    bf16* __restrict__ S,
    const float* __restrict__ wih, const float* __restrict__ whh,
    const float* __restrict__ bih, const float* __restrict__ bhh,
    const float* __restrict__ attW, const float* __restrict__ att1,
    const float* __restrict__ att2,
    bf16* __restrict__ xt, float* __restrict__ s1, float* __restrict__ s2){
  __shared__ float ol[4][16][33];
  int wid  = (blockIdx.x*THREADS + threadIdx.x) >> 6;
  int wv   = threadIdx.x >> 6;
  int lane = threadIdx.x & 63;
  int cl = lane & 15;
  int kb = lane >> 4;
  short8v BW[12], BT[2];
  #pragma unroll
  for (int g = 0; g < 6; g++){
    const float* wr = wih + (size_t)(g*16 + cl)*32 + kb*8;
    const float* vr = whh + (size_t)(g*16 + cl)*32 + kb*8;
    short8v bw, bv;
    #pragma unroll
    for (int j = 0; j < 8; j++){ bw[j] = (short)bfbits(wr[j]); bv[j] = (short)bfbits(vr[j]); }
    BW[g] = bw; BW[6+g] = bv;
  }
  #pragma unroll
  for (int g = 0; g < 2; g++){
    short8v bt;
    #pragma unroll
    for (int j = 0; j < 8; j++) bt[j] = (short)bfbits(attW[(size_t)(g*16+cl)*32 + kb*8 + j]);
    BT[g] = bt;
  }
  float bI[6], bH[6];
  #pragma unroll
  for (int g = 0; g < 6; g++){ bI[g] = bih[g*16 + cl]; bH[g] = bhh[g*16 + cl]; }
  float a1c0 = att1[cl], a1c1 = att1[16+cl];
  float a2c0 = att2 ? att2[cl] : 0.f, a2c1 = att2 ? att2[16+cl] : 0.f;
  f32x4 zero; zero[0]=0.f; zero[1]=0.f; zero[2]=0.f; zero[3]=0.f;

  for (int t = 0; t < 8; t++){
    int nb = (wid*8 + t) * 16;
    short8v Ah = *(const short8v*)(HV + (size_t)(nb + cl)*32 + kb*8);
    short8v Ax = *(const short8v*)(S  + (size_t)(nb + cl)*32 + kb*8);
    f32x4 gi[6], gh[6];
    #pragma unroll
    for (int g = 0; g < 6; g++){
      f32x4 a, b;
      #pragma unroll
      for (int q = 0; q < 4; q++){ a[q] = bI[g]; b[q] = bH[g]; }
      gi[g] = __builtin_amdgcn_mfma_f32_16x16x32_bf16(Ah, BW[g],   a, 0, 0, 0);
      gh[g] = __builtin_amdgcn_mfma_f32_16x16x32_bf16(Ax, BW[6+g], b, 0, 0, 0);
    }
    #pragma unroll
    for (int r = 0; r < 4; r++){
      int node = nb + kb*4 + r;
      bf16* srow = S + (size_t)node*32;
      float x0 = b2f(srow[cl]), x1 = b2f(srow[16 + cl]);
      float r0 = sigm(gi[0][r] + gh[0][r]);
      float z0 = sigm(gi[2][r] + gh[2][r]);
      float n0 = tanh_fast(gi[4][r] + r0*gh[4][r]);
      float r1 = sigm(gi[1][r] + gh[1][r]);
      float z1 = sigm(gi[3][r] + gh[3][r]);
      float n1 = tanh_fast(gi[5][r] + r1*gh[5][r]);
      float o0 = fmaxf((1.f - z0)*n0 + z0*x0, 0.f);
      float o1 = fmaxf((1.f - z1)*n1 + z1*x1, 0.f);
      srow[cl]      = f2b(o0);
      srow[16 + cl] = f2b(o1);
      ol[wv][kb*4 + r][cl]      = o0;
      ol[wv][kb*4 + r][16 + cl] = o1;
    }
    __syncthreads();
    short8v Ao;
    #pragma unroll
    for (int j = 0; j < 8; j++) Ao[j] = (short)bfbits(ol[wv][cl][kb*8 + j]);
    f32x4 t0 = __builtin_amdgcn_mfma_f32_16x16x32_bf16(Ao, BT[0], zero, 0, 0, 0);
    f32x4 t1 = __builtin_amdgcn_mfma_f32_16x16x32_bf16(Ao, BT[1], zero, 0, 0, 0);
    #pragma unroll
    for (int r = 0; r < 4; r++){
      int node = nb + kb*4 + r;
      bf16* xrow = xt + (size_t)node*32;
      xrow[cl]      = f2b(t0[r]);
      xrow[16 + cl] = f2b(t1[r]);
      float p1 = t0[r]*a1c0 + t1[r]*a1c1;
      p1 += __shfl_xor(p1, 1, 16);
      p1 += __shfl_xor(p1, 2, 16);
      p1 += __shfl_xor(p1, 4, 16);
      p1 += __shfl_xor(p1, 8, 16);
      if (cl == 0) s1[node] = p1;
      if (att2){
        float p2 = t0[r]*a2c0 + t1[r]*a2c1;
        p2 += __shfl_xor(p2, 1, 16);
        p2 += __shfl_xor(p2, 2, 16);
        p2 += __shfl_xor(p2, 4, 16);
        p2 += __shfl_xor(p2, 8, 16);
        if (cl == 0) s2[node] = p2;
      }
    }
    __syncthreads();
  }
}

// ---- conv v5: 4 nodes per 32-lane group (8 lanes/node) — full-util score pass.
__global__ __launch_bounds__(THREADS) void k_conv(const int* __restrict__ rowptr,
    const int2* __restrict__ epk, const bf16* __restrict__ U,
    const float* __restrict__ w1 /*32x33*/, const float* __restrict__ attl,
    const float* __restrict__ alsrc, const float* __restrict__ term,
    const bf16* __restrict__ ROWS, int rstride, int voff,
    const float* __restrict__ bias, bf16* __restrict__ HV){
  int grp = blockIdx.x*(THREADS/32) + (threadIdx.x >> 5);
  int c32 = threadIdx.x & 31;
  int sub = c32 >> 3;          // node within group (0..3)
  int l8  = c32 & 7;           // lane within node
  int node = grp*4 + sub;
  int ws = rowptr[node], we = rowptr[node+1];
  float tv = term[node];
  float wc[32], at[32];        // wave-uniform -> SGPRs
  if (U){
    #pragma unroll
    for (int j = 0; j < 32; j++){ wc[j] = w1[j*33 + 32]; at[j] = attl[j]; }
  }
  int eh = l8 >> 2, cb = l8 & 3;
  float sl = 0.f;
  float acc[8];
  #pragma unroll
  for (int j = 0; j < 8; j++) acc[j] = 0.f;
  for (int p0 = ws; p0 < we; p0 += 8){
    int p = p0 + l8;
    bool ok = p < we;
    int pc = ok ? p : ws;
    int2 pk = epk[pc];
    int siA = pk.x;
    float sc;
    if (U){
      float a = __int_as_float(pk.y);
      const short8v* ur = (const short8v*)(U + (size_t)siA*64);  // u-half of UV row
      sc = 0.f;
      #pragma unroll
      for (int q = 0; q < 4; q++){
        short8v u8 = ur[q];
        #pragma unroll
        for (int j = 0; j < 8; j++)
          sc += at[q*8+j]*lrelu(s2f(u8[j]) + a*wc[q*8+j]);
      }
    } else {
      sc = alsrc[siA];
    }
    float wme = ok ? __expf(lrelu(sc + tv)) : 0.f;
    sl += wme;
    #pragma unroll
    for (int se = 0; se < 4; se++){
      if (p0 + se*2 >= we) break;
      int lsrc = sub*8 + se*2 + eh;
      float w = __shfl(wme, lsrc, 32);
      int si  = __shfl(siA, lsrc, 32);
      short8v r8 = *(const short8v*)(ROWS + (size_t)si*rstride + voff + cb*8);
      #pragma unroll
      for (int j = 0; j < 8; j++) acc[j] += s2f(r8[j]) * w;
    }
  }
  // denominator: sum over the 8 lanes of this sub-group
  sl += __shfl_xor(sl, 1, 32);
  sl += __shfl_xor(sl, 2, 32);
  sl += __shfl_xor(sl, 4, 32);
  float inv = 1.f/(sl + 1e-16f);
  // combine the eh pair
  #pragma unroll
  for (int j = 0; j < 8; j++) acc[j] += __shfl_xor(acc[j], 4, 32);
  if (eh == 0){
    unsigned int o[4];
    #pragma unroll
    for (int j2 = 0; j2 < 4; j2++){
      float h0 = eluf(acc[2*j2  ]*inv + bias[cb*8 + 2*j2  ]);
      float h1 = eluf(acc[2*j2+1]*inv + bias[cb*8 + 2*j2+1]);
      o[j2] = pack2(h0, h1);
    }
    *(uint4*)(HV + (size_t)node*32 + cb*8) = make_uint4(o[0], o[1], o[2], o[3]);
  }
}

// ======== fused readout: rsum + q + 2x(softmax+GRU3) + final mish ===========
__global__ __launch_bounds__(THREADS) void k_readout(const int* __restrict__ gptr,
    const bf16* __restrict__ X, const float* __restrict__ anode,
    const bf16* __restrict__ XS,
    const float* __restrict__ mw /*m_lin_w*/, const float* __restrict__ mattd,
    const float* __restrict__ mbias,
    const float* __restrict__ wih, const float* __restrict__ whh,
    const float* __restrict__ bih, const float* __restrict__ bhh,
    const float* __restrict__ lin2_w, const float* __restrict__ lin2_b,
    float* __restrict__ y){
  int g = blockIdx.x*(THREADS/32) + (threadIdx.x >> 5);
  int c = threadIdx.x & 31;
  int gs = gptr[g], ge = gptr[g+1];
  // rsum + relu
  float out = 0.f;
  for (int n = gs; n < ge; n++) out += b2f(X[(size_t)n*32 + c]);
  out = fmaxf(out, 0.f);
  // q[c]
  float qc = 0.f;
  #pragma unroll
  for (int j = 0; j < 32; j++) qc += mattd[j]*mw[j*32 + c];
  // 2 timesteps
  #pragma unroll 1
  for (int t = 0; t < 2; t++){
    float ag = redsum32(out * qc);
    float s = 0.f;
    for (int p0 = gs; p0 < ge; p0 += 32){
      int p = p0 + c;
      float e = (p < ge) ? __expf(lrelu(anode[p] + ag)) : 0.f;
      s += redsum32(e);
    }
    float inv = 1.f/(s + 1e-16f);
    float acc = 0.f;
    int n = gs;
    for (; n + 4 <= ge; n += 4){
      float e0 = __expf(lrelu(anode[n]   + ag));
      float e1 = __expf(lrelu(anode[n+1] + ag));
      float e2 = __expf(lrelu(anode[n+2] + ag));
      float e3 = __expf(lrelu(anode[n+3] + ag));
      acc += b2f(XS[(size_t)(n  )*32 + c])*e0 + b2f(XS[(size_t)(n+1)*32 + c])*e1
           + b2f(XS[(size_t)(n+2)*32 + c])*e2 + b2f(XS[(size_t)(n+3)*32 + c])*e3;
    }
    for (; n < ge; n++)
      acc += b2f(XS[(size_t)n*32 + c]) * __expf(lrelu(anode[n] + ag));
    acc *= inv;
    float hv = eluf(acc + mbias[c]);
    out = gru_relu(hv, out, c, wih, whh, bih, bhh);
  }
  // final: y = mish(out @ lin2^T + b)
  #pragma unroll
  for (int oc2 = 0; oc2 < 2; oc2++){
    int oc = oc2*32 + c;
    float facc = lin2_b[oc];
    const float* wr = lin2_w + (size_t)oc*32;
    #pragma unroll 8
    for (int k = 0; k < 32; k++) facc += __shfl(out, k, 32) * wr[k];
    float sp = fmaxf(facc, 0.f) + log1pf(expf(-fabsf(facc)));  // precise (final output)
    y[(size_t)g*64 + oc] = facc * tanhf(sp);
  }
}

extern "C" void kernel_launch(void* const* d_in, const int* in_sizes, int n_in,
                              void* d_out, int out_size, void* d_ws, size_t ws_size,
                              hipStream_t stream){
  const float* x_in     = (const float*)d_in[0];
  const float* ea       = (const float*)d_in[1];
  const int*   ei       = (const int*)  d_in[2];
  const int*   batch    = (const int*)  d_in[3];
  const float* lin1_w   = (const float*)d_in[4];
  const float* lin1_b   = (const float*)d_in[5];
  const float* g_lin1_w = (const float*)d_in[6];
  const float* g_lin2_w = (const float*)d_in[7];
  const float* g_att_l  = (const float*)d_in[8];
  const float* g_att_r  = (const float*)d_in[9];
  const float* g_bias   = (const float*)d_in[10];
  const float* gru1_wih = (const float*)d_in[11];
  const float* gru1_whh = (const float*)d_in[12];
  const float* gru1_bih = (const float*)d_in[13];
  const float* gru1_bhh = (const float*)d_in[14];
  const float* a_lin_w  = (const float*)d_in[15];
  const float* a_att_src= (const float*)d_in[16];
  const float* a_att_dst= (const float*)d_in[17];
  const float* a_bias   = (const float*)d_in[18];
  const float* gru2_wih = (const float*)d_in[19];
  const float* gru2_whh = (const float*)d_in[20];
  const float* gru2_bih = (const float*)d_in[21];
  const float* gru2_bhh = (const float*)d_in[22];
  const float* m_lin_w  = (const float*)d_in[23];
  const float* m_att_src= (const float*)d_in[24];
  const float* m_att_dst= (const float*)d_in[25];
  const float* m_bias   = (const float*)d_in[26];
  const float* gru3_wih = (const float*)d_in[27];
  const float* gru3_whh = (const float*)d_in[28];
  const float* gru3_bih = (const float*)d_in[29];
  const float* gru3_bhh = (const float*)d_in[30];
  const float* lin2_w   = (const float*)d_in[31];
  const float* lin2_b   = (const float*)d_in[32];

  float* W = (float*)d_ws;
  bf16*  XB    = (bf16*)W;               // NN*32 bf16 node state (16MB)
  bf16*  UV    = (bf16*)(W + 8388608);   // NN*64 bf16 interleaved u|v (32MB)
  bf16*  XT    = (bf16*)(W + 8388608);   // NN*32 bf16 : xt/xs (reuses UV after conv1)
  int2*  EPK   = (int2*) (W + 16777216); // NE x (src, ea-bits)
  int*   RP1   = (int*)  (W + 20971520); // NN partial scan (dead after k_mid)
  bf16*  BC    = (bf16*) (W + 20971520); // NN*32 bf16 : h1 / h2 (after mid)
  int*   RANK  = (int*)  (W + 23068672); // NE within-dst ranks
  int*   ROWPTR= (int*)  (W + 25165824); // NN+1 (pad)
  int*   HIST  = (int*)  (W + 25428032); // NN
  int*   BTOT  = (int*)  (W + 25690176); // 1024 (raw chunk totals)
  float* NS1   = W + 25691200;           // NN : nr / al / a_node
  float* NS2   = W + 25953344;           // NN : ar
  int*   GPTR  = (int*)  (W + 26215488); // NG+1 (pad)

  dim3 b(THREADS);
  const int gNode  = NN/THREADS;        // 1024
  const int gConv  = NN/32;             // 8192 : conv v5 (32 nodes/block)
  const int gMFMA  = NN/(16*8*4);       // 512
  const int gRO    = NG/(THREADS/32);   // 1024

  // zero HIST (must precede k_front's histrank section)
  hipMemsetAsync(HIST, 0, (size_t)NN*sizeof(int), stream);

  // FRONT: embed (MFMA, bf16 X + interleaved UV) ∥ histrank (atomics) ∥ gptr
  k_front<<<FB_EMBED + FB_HIST + FB_GPTR, b, 0, stream>>>(
      x_in, lin1_w, lin1_b, g_lin1_w, g_lin2_w, g_att_r, XB, UV, NS1,
      ei, HIST, RANK, batch, GPTR);

  // scan1; MID: local btot scan + (final rowptr ∥ atomic-free place)
  k_scan1<<<gNode, b, 0, stream>>>(HIST, RP1, BTOT);
  k_mid<<<MB_SCAN + NE/THREADS, b, 0, stream>>>(RP1, BTOT, ROWPTR, ei, ea, RANK, EPK);

  // GATEConv (inline score from UV u-half; gather v-half, stride 64, voff 32) + GRU1
  k_conv<<<gConv, b, 0, stream>>>(ROWPTR, EPK, UV, g_lin1_w, g_att_l,
      nullptr, NS1, UV, 64, 32, g_bias, BC);
  k_gru_att<<<gMFMA, b, 0, stream>>>(BC, XB, gru1_wih, gru1_whh, gru1_bih, gru1_bhh,
      a_lin_w, a_att_src, a_att_dst, XT, NS1, NS2);

  // GATConv (score = al[src]+ar[dst]; gather xt, stride 32) + GRU2
  k_conv<<<gConv, b, 0, stream>>>(ROWPTR, EPK, nullptr, nullptr, nullptr,
      NS1, NS2, XT, 32, 0, a_bias, BC);
  k_gru_att<<<gMFMA, b, 0, stream>>>(BC, XB, gru2_wih, gru2_whh, gru2_bih, gru2_bhh,
      m_lin_w, m_att_src, nullptr, XT, NS1, nullptr);

  // fused readout: rsum + q + 2x(softmax+GRU3) + final mish
  k_readout<<<gRO, b, 0, stream>>>(GPTR, XB, NS1, XT, m_lin_w, m_att_dst, m_bias,
      gru3_wih, gru3_whh, gru3_bih, gru3_bhh, lin2_w, lin2_b, (float*)d_out);
}